// Round 5
// baseline (135.775 us; speedup 1.0000x reference)
//
#include <hip/hip_runtime.h>
#include <hip/hip_bf16.h>

#define N_NODES 4096
#define IN_F 256
#define OUT_F 64
#define HEADS 8
#define ALPHA 0.2f

typedef _Float16 f16x8 __attribute__((ext_vector_type(8)));
typedef float f32x4 __attribute__((ext_vector_type(4)));
union U4 { uint4 u; f16x8 h; unsigned w[4]; };

// ---- workspace layout (bytes) ----
#define XF_OFF    0                                 // 2 MB  f16 X
#define WFRAG_OFF (XF_OFF + 4096*256*2)             // 256 KB f16 W B-frags
#define BFRAG_OFF (WFRAG_OFF + 8*8*4*64*8*2)        // 4 MB  f16 H B-frags
#define F1_OFF    (BFRAG_OFF + 8*128*4*64*8*2)
#define F2_OFF    (F1_OFF + 8*4096*4)
#define FMAX_OFF  (F2_OFF + 8*4096*4)
#define GP_OFF    (FMAX_OFF + 256)                  // 64 KB f16 exp(f2)
#define GN_OFF    (GP_OFF + 8*4096*2)               // 64 KB f16 exp(a*f2)
#define ADJ_OFF   (GN_OFF + 8*4096*2)               // 2 MB adjacency bitmask
#define HPART_OFF (ADJ_OFF + 2097152)               // 8 MB per-head outputs

static __device__ __forceinline__ unsigned pkmul(unsigned a, unsigned b) {
  unsigned r; asm("v_pk_mul_f16 %0, %1, %2" : "=v"(r) : "v"(a), "v"(b)); return r;
}
static __device__ __forceinline__ unsigned pkmax(unsigned a, unsigned b) {
  unsigned r; asm("v_pk_max_f16 %0, %1, %2" : "=v"(r) : "v"(a), "v"(b)); return r;
}
static __device__ __forceinline__ unsigned short f2h_bits(float f) {
  return __builtin_bit_cast(unsigned short, (_Float16)f);
}

// k_misc: [0,2048) adj->bitmask; [2048,2112) X->f16; [2112,2120) W B-frags;
//         [2120,2184) f1/f2 (wa computed redundantly per block in LDS)
__global__ __launch_bounds__(256) void k_misc(
    const float* __restrict__ X, const int* __restrict__ adj,
    const float* __restrict__ W, const float* __restrict__ a,
    _Float16* __restrict__ Xf, unsigned long long* __restrict__ bits,
    _Float16* __restrict__ wfrag, float* __restrict__ f1, float* __restrict__ f2) {
  __shared__ float sh[4096];                       // 16 KB: wa tables / reduction
  int b = blockIdx.x, t = threadIdx.x;
  if (b < 2048) {
    int lane = t & 63;
    int waveid = b * 4 + (t >> 6);
    for (int it = 0; it < 32; ++it) {
      int widx = waveid + it * 8192;
      int v = adj[(size_t)widx * 64 + lane];
      unsigned long long m = __ballot(v != 0);
      if (lane == 0) bits[widx] = m;
    }
  } else if (b < 2112) {
    int tid = (b - 2048) * 256 + t;
#pragma unroll
    for (int it = 0; it < 8; ++it) {
      int idx = (it * 16384 + tid) * 8;
      float4 xa = *(const float4*)(X + idx);
      float4 xc = *(const float4*)(X + idx + 4);
      U4 o;
      o.h[0] = (_Float16)xa.x; o.h[1] = (_Float16)xa.y;
      o.h[2] = (_Float16)xa.z; o.h[3] = (_Float16)xa.w;
      o.h[4] = (_Float16)xc.x; o.h[5] = (_Float16)xc.y;
      o.h[6] = (_Float16)xc.z; o.h[7] = (_Float16)xc.w;
      *(U4*)(Xf + idx) = o;
    }
  } else if (b < 2120) {
    int h = b - 2112;
    for (int pos = t; pos < 2048; pos += 256) {
      int kt = pos >> 8, ct = (pos >> 6) & 3, l = pos & 63;
      int lr = l & 15, lg = l >> 4;
#pragma unroll
      for (int e = 0; e < 8; ++e)
        wfrag[(size_t)(((h*8 + kt)*4 + ct)*64 + l) * 8 + e]
          = (_Float16)W[(size_t)(h*256 + kt*32 + lg*8 + e) * 64 + ct*16 + lr];
    }
  } else {
    // ---- f1/f2: wa into LDS, then 64-row dot products ----
    float (*wa_s)[8][256] = (float (*)[8][256])sh;   // [2][8][256]
    for (int e = t; e < 2048; e += 256) {
      int h = e >> 8, k = e & 255;
      const float* Wr = W + ((size_t)h * IN_F + k) * OUT_F;
      const float* a1 = a + (size_t)h * 2 * OUT_F;
      const float* a2 = a1 + OUT_F;
      float s1 = 0.f, s2 = 0.f;
#pragma unroll
      for (int f = 0; f < OUT_F; f += 4) {
        float4 wv = *(const float4*)(Wr + f);
        float4 v1 = *(const float4*)(a1 + f);
        float4 v2 = *(const float4*)(a2 + f);
        s1 += wv.x*v1.x + wv.y*v1.y + wv.z*v1.z + wv.w*v1.w;
        s2 += wv.x*v2.x + wv.y*v2.y + wv.z*v2.z + wv.w*v2.w;
      }
      wa_s[0][h][k] = s1;
      wa_s[1][h][k] = s2;
    }
    __syncthreads();
    int bb = b - 2120, l = t & 63;
    int wq = __builtin_amdgcn_readfirstlane(t >> 6);
    int i = bb * 64 + l;
    const float* xr = X + (size_t)i * 256 + wq * 64;
    float s1[8] = {0,0,0,0,0,0,0,0}, s2[8] = {0,0,0,0,0,0,0,0};
#pragma unroll 4
    for (int k = 0; k < 64; k += 4) {
      float4 xv = *(const float4*)(xr + k);
#pragma unroll
      for (int h = 0; h < 8; ++h) {
        float4 v1 = *(const float4*)(&wa_s[0][h][wq*64 + k]);
        float4 v2 = *(const float4*)(&wa_s[1][h][wq*64 + k]);
        s1[h] += xv.x*v1.x + xv.y*v1.y + xv.z*v1.z + xv.w*v1.w;
        s2[h] += xv.x*v2.x + xv.y*v2.y + xv.z*v2.z + xv.w*v2.w;
      }
    }
    __syncthreads();                               // wa reads done; reuse sh as red
    float (*red)[64][16] = (float (*)[64][16])sh;  // [3][64][16]
    if (wq > 0) {
#pragma unroll
      for (int h = 0; h < 8; ++h) {
        red[wq-1][l][h] = s1[h];
        red[wq-1][l][h+8] = s2[h];
      }
    }
    __syncthreads();
    if (wq == 0) {
#pragma unroll
      for (int h = 0; h < 8; ++h) {
#pragma unroll
        for (int q = 0; q < 3; ++q) { s1[h] += red[q][l][h]; s2[h] += red[q][l][h+8]; }
        f1[h*4096 + i] = s1[h];
        f2[h*4096 + i] = s2[h];
      }
    }
  }
}

// k_hf: [0,256) H=X@W (f16 MFMA) -> B-frag layout; [256,264) fmax + G tables
__global__ __launch_bounds__(256) void k_hf(
    const _Float16* __restrict__ Xf, const _Float16* __restrict__ wfrag,
    const float* __restrict__ f2, _Float16* __restrict__ bfrag,
    float* __restrict__ fmx, _Float16* __restrict__ Gp, _Float16* __restrict__ Gn) {
  int b = blockIdx.x, t = threadIdx.x;
  if (b < 256) {
    int h = b & 7, rb = b >> 3;
    int w = t >> 6, l = t & 63;
    int i0 = rb * 128 + w * 32;
    int r = l & 15, g = l >> 4;
    const U4* xv = (const U4*)Xf;
    const U4* wv = (const U4*)wfrag;
    f32x4 z = {0.f, 0.f, 0.f, 0.f};
    f32x4 acc[2][4] = {{z,z,z,z},{z,z,z,z}};
#pragma unroll
    for (int kt = 0; kt < 8; ++kt) {
      U4 a0 = xv[(i0 + r) * 32 + kt*4 + g];
      U4 a1 = xv[(i0 + 16 + r) * 32 + kt*4 + g];
#pragma unroll
      for (int ct = 0; ct < 4; ++ct) {
        U4 bv = wv[((h*8 + kt)*4 + ct)*64 + l];
        acc[0][ct] = __builtin_amdgcn_mfma_f32_16x16x32_f16(a0.h, bv.h, acc[0][ct], 0, 0, 0);
        acc[1][ct] = __builtin_amdgcn_mfma_f32_16x16x32_f16(a1.h, bv.h, acc[1][ct], 0, 0, 0);
      }
    }
#pragma unroll
    for (int rt2 = 0; rt2 < 2; ++rt2)
#pragma unroll
      for (int ct = 0; ct < 4; ++ct) {
        int jb = i0 + rt2*16 + g*4;                // 4 consecutive j, same upper idx
        size_t base = ((((size_t)h*128 + (jb>>5))*4 + ct)*64 + ((jb>>3)&3)*16 + r) * 8
                      + (jb & 7);
        union { short4 s; _Float16 hh[4]; } sv;
#pragma unroll
        for (int ri = 0; ri < 4; ++ri) sv.hh[ri] = (_Float16)acc[rt2][ct][ri];
        *(short4*)(bfrag + base) = sv.s;
      }
  } else {
    __shared__ float sm[4];
    int h = b - 256;
    const float* f = f2 + h * 4096;
    float m = -1e30f;
    for (int i = t; i < 4096; i += 256) m = fmaxf(m, f[i]);
#pragma unroll
    for (int off = 32; off >= 1; off >>= 1) m = fmaxf(m, __shfl_xor(m, off, 64));
    if ((t & 63) == 0) sm[t >> 6] = m;
    __syncthreads();
    if (t == 0) fmx[h] = fmaxf(fmaxf(sm[0], sm[1]), fmaxf(sm[2], sm[3]));
    for (int i = t; i < 4096; i += 256) {
      float v = f[i];
      Gp[h*4096 + i] = (_Float16)__expf(v);
      Gn[h*4096 + i] = (_Float16)__expf(ALPHA * v);
    }
  }
}

// k_attn v3: block=(head, 64 rows); 4 waves = 4 rowgroups of 16, full j sweep.
// B tile (4KB/jt) staged via reg double-buffer into LDS, shared by all waves.
__global__ __launch_bounds__(256) void k_attn(
    const float* __restrict__ f1, const float* __restrict__ f2max,
    const unsigned int* __restrict__ adjbits, const _Float16* __restrict__ Gp,
    const _Float16* __restrict__ Gn, const _Float16* __restrict__ bfrag,
    float* __restrict__ hpart) {
  __shared__ unsigned Lb[64][129];                 // 33 KB adjacency bits
  __shared__ U4 Bst[2][256];                       // 8 KB B double-buffer
  __shared__ U4 Gs[2][512];                        // 16 KB Gp/Gn head slices
  __shared__ unsigned MLUT[4];
  int b = blockIdx.x;
  int h = b & 7, rb = b >> 3;                      // head <-> XCD L2 locality
  int i0 = rb * 64;
  int t = threadIdx.x, w = t >> 6, l = t & 63;
  int r = l & 15, g = l >> 4, g8 = g * 8;
  if (t < 4) MLUT[t] = ((t & 1) ? 0xFFFFu : 0u) | ((t & 2) ? 0xFFFF0000u : 0u);
  const uint4* bfh = (const uint4*)bfrag + (size_t)h * (128 * 256);
  uint4 rB0 = bfh[t];                              // jt=0 tile
  uint4 rB = bfh[256 + t];                         // jt=1 tile (prefetch)
  for (int q = t; q < 64 * 128; q += 256)
    Lb[q >> 7][q & 127] = adjbits[(size_t)(i0 + (q >> 7)) * 128 + (q & 127)];
  {
    const uint4* gp4 = (const uint4*)(Gp + (size_t)h * 4096);
    const uint4* gn4 = (const uint4*)(Gn + (size_t)h * 4096);
#pragma unroll
    for (int q = 0; q < 2; ++q) {
      Gs[0][q * 256 + t].u = gp4[q * 256 + t];
      Gs[1][q * 256 + t].u = gn4[q * 256 + t];
    }
  }
  int row = i0 + w * 16 + r;
  float F2m = f2max[h];
  float f1r = f1[h * N_NODES + row];
  float sM = f1r + F2m;
  float M = fmaxf(sM, ALPHA * sM);                 // row-max upper bound (monotone lrelu)
  unsigned short ep = f2h_bits(__expf(f1r - M));
  unsigned short en = f2h_bits(__expf(ALPHA * f1r - M));
  unsigned Epp = ep | ((unsigned)ep << 16), Enn = en | ((unsigned)en << 16);
  unsigned ov = (r == 0) ? 0x3C003C00u : 0u;       // ones column B-frag (f16 1.0)
  U4 bones; bones.u = make_uint4(ov, ov, ov, ov);
  Bst[0][t].u = rB0;
  __syncthreads();
  f32x4 z = {0.f,0.f,0.f,0.f};
  f32x4 acc0 = z, acc1 = z, acc2 = z, acc3 = z, dn = z;
  int w16 = w * 16;
  int cur = 0;
  for (int jt = 0; jt < 128; ++jt) {
    uint4 rN;
    if (jt < 126) rN = bfh[(jt + 2) * 256 + t];    // prefetch 2 ahead
    unsigned wm = Lb[w16 + r][jt];
    U4 gp, gn, av;
    gp.u = Gs[0][jt * 4 + g].u;
    gn.u = Gs[1][jt * 4 + g].u;
#pragma unroll
    for (int p = 0; p < 4; ++p) {
      unsigned pm = pkmax(pkmul(Epp, gp.w[p]), pkmul(Enn, gn.w[p]));
      av.w[p] = pm & MLUT[(wm >> (g8 + 2*p)) & 3];
    }
    U4 b0, b1, b2, b3;
    b0.u = Bst[cur][l].u;       b1.u = Bst[cur][64 + l].u;
    b2.u = Bst[cur][128 + l].u; b3.u = Bst[cur][192 + l].u;
    acc0 = __builtin_amdgcn_mfma_f32_16x16x32_f16(av.h, b0.h, acc0, 0, 0, 0);
    acc1 = __builtin_amdgcn_mfma_f32_16x16x32_f16(av.h, b1.h, acc1, 0, 0, 0);
    acc2 = __builtin_amdgcn_mfma_f32_16x16x32_f16(av.h, b2.h, acc2, 0, 0, 0);
    acc3 = __builtin_amdgcn_mfma_f32_16x16x32_f16(av.h, b3.h, acc3, 0, 0, 0);
    dn   = __builtin_amdgcn_mfma_f32_16x16x32_f16(av.h, bones.h, dn, 0, 0, 0);
    if (jt < 127) Bst[cur ^ 1][t].u = rB;          // write next tile
    rB = rN;
    __syncthreads();
    cur ^= 1;
  }
#pragma unroll
  for (int ri = 0; ri < 4; ++ri) {
    float den = __shfl(dn[ri], l & 48);            // D col 0 holds row-sum
    float sc = 0.125f / den;
    float* hp = hpart + ((size_t)h * N_NODES + i0 + w16 + g*4 + ri) * 64;
    hp[r]      = acc0[ri] * sc;
    hp[16 + r] = acc1[ri] * sc;
    hp[32 + r] = acc2[ri] * sc;
    hp[48 + r] = acc3[ri] * sc;
  }
}

// out = sum_h hpart[h]  (0.125 already folded in)
__global__ __launch_bounds__(256) void k_hmean(const float* __restrict__ hpart,
                                               float* __restrict__ out) {
  int idx = blockIdx.x * 256 + threadIdx.x;
  const float4* hp = (const float4*)hpart;
  float4 s = hp[idx];
#pragma unroll
  for (int h = 1; h < 8; ++h) {
    float4 v = hp[h * 65536 + idx];
    s.x += v.x; s.y += v.y; s.z += v.z; s.w += v.w;
  }
  ((float4*)out)[idx] = s;
}

extern "C" void kernel_launch(void* const* d_in, const int* in_sizes, int n_in,
                              void* d_out, int out_size, void* d_ws, size_t ws_size,
                              hipStream_t stream) {
  const float* X = (const float*)d_in[0];
  const int* adj = (const int*)d_in[1];
  const float* W = (const float*)d_in[2];
  const float* a = (const float*)d_in[3];
  float* out = (float*)d_out;
  char* ws = (char*)d_ws;

  _Float16* Xf    = (_Float16*)(ws + XF_OFF);
  _Float16* wfrag = (_Float16*)(ws + WFRAG_OFF);
  _Float16* bfrag = (_Float16*)(ws + BFRAG_OFF);
  float* f1  = (float*)(ws + F1_OFF);
  float* f2  = (float*)(ws + F2_OFF);
  float* fmx = (float*)(ws + FMAX_OFF);
  _Float16* Gp = (_Float16*)(ws + GP_OFF);
  _Float16* Gn = (_Float16*)(ws + GN_OFF);
  unsigned long long* bits64 = (unsigned long long*)(ws + ADJ_OFF);
  const unsigned int* bits32 = (const unsigned int*)(ws + ADJ_OFF);
  float* hpart = (float*)(ws + HPART_OFF);

  k_misc<<<dim3(2184), dim3(256), 0, stream>>>(X, adj, W, a, Xf, bits64, wfrag, f1, f2);
  k_hf<<<dim3(264), dim3(256), 0, stream>>>(Xf, wfrag, f2, bfrag, fmx, Gp, Gn);
  k_attn<<<dim3(512), dim3(256), 0, stream>>>(f1, fmx, bits32, Gp, Gn, bfrag, hpart);
  k_hmean<<<dim3(256), dim3(256), 0, stream>>>(hpart, out);
}

// Round 6
// 87.124 us; speedup vs baseline: 1.5584x; 1.5584x over previous
//
#include <hip/hip_runtime.h>
#include <hip/hip_bf16.h>

#define N_NODES 4096
#define IN_F 256
#define OUT_F 64
#define HEADS 8
#define ALPHA 0.2f

typedef _Float16 f16x8 __attribute__((ext_vector_type(8)));
typedef float f32x4 __attribute__((ext_vector_type(4)));
union U4 { uint4 u; f16x8 h; unsigned w[4]; };

// ---- workspace layout (bytes) ----
#define XF_OFF    0                                 // 2 MB  f16 X
#define WFRAG_OFF (XF_OFF + 4096*256*2)             // 256 KB f16 W B-frags
#define BFRAG_OFF (WFRAG_OFF + 8*8*4*64*8*2)        // 4 MB  f16 H B-frags
#define F1_OFF    (BFRAG_OFF + 8*128*4*64*8*2)
#define F2_OFF    (F1_OFF + 8*4096*4)
#define FMAX_OFF  (F2_OFF + 8*4096*4)
#define GP_OFF    (FMAX_OFF + 256)                  // 64 KB f16 exp(f2)
#define GN_OFF    (GP_OFF + 8*4096*2)               // 64 KB f16 exp(a*f2)
#define ADJ_OFF   (GN_OFF + 8*4096*2)               // 2 MB adjacency bitmask
#define HPART_OFF (ADJ_OFF + 2097152)               // 8 MB per-head outputs

static __device__ __forceinline__ unsigned pkmul(unsigned a, unsigned b) {
  unsigned r; asm("v_pk_mul_f16 %0, %1, %2" : "=v"(r) : "v"(a), "v"(b)); return r;
}
static __device__ __forceinline__ unsigned pkmax(unsigned a, unsigned b) {
  unsigned r; asm("v_pk_max_f16 %0, %1, %2" : "=v"(r) : "v"(a), "v"(b)); return r;
}
static __device__ __forceinline__ unsigned pkadd(unsigned a, unsigned b) {
  unsigned r; asm("v_pk_add_f16 %0, %1, %2" : "=v"(r) : "v"(a), "v"(b)); return r;
}
static __device__ __forceinline__ unsigned short f2h_bits(float f) {
  return __builtin_bit_cast(unsigned short, (_Float16)f);
}
static __device__ __forceinline__ float pk_lo(unsigned w) {
  return (float)__builtin_bit_cast(_Float16, (unsigned short)(w & 0xFFFFu));
}
static __device__ __forceinline__ float pk_hi(unsigned w) {
  return (float)__builtin_bit_cast(_Float16, (unsigned short)(w >> 16));
}

// k_misc: [0,2048) adj->bitmask; [2048,2112) X->f16; [2112,2120) W B-frags
__global__ __launch_bounds__(256) void k_misc(
    const float* __restrict__ X, const int* __restrict__ adj,
    const float* __restrict__ W, _Float16* __restrict__ Xf,
    unsigned long long* __restrict__ bits, _Float16* __restrict__ wfrag) {
  int b = blockIdx.x, t = threadIdx.x;
  if (b < 2048) {
    int lane = t & 63;
    int waveid = b * 4 + (t >> 6);
    for (int it = 0; it < 32; ++it) {
      int widx = waveid + it * 8192;
      int v = adj[(size_t)widx * 64 + lane];
      unsigned long long m = __ballot(v != 0);
      if (lane == 0) bits[widx] = m;
    }
  } else if (b < 2112) {
    int tid = (b - 2048) * 256 + t;
#pragma unroll
    for (int it = 0; it < 8; ++it) {
      int idx = (it * 16384 + tid) * 8;
      float4 xa = *(const float4*)(X + idx);
      float4 xc = *(const float4*)(X + idx + 4);
      U4 o;
      o.h[0] = (_Float16)xa.x; o.h[1] = (_Float16)xa.y;
      o.h[2] = (_Float16)xa.z; o.h[3] = (_Float16)xa.w;
      o.h[4] = (_Float16)xc.x; o.h[5] = (_Float16)xc.y;
      o.h[6] = (_Float16)xc.z; o.h[7] = (_Float16)xc.w;
      *(U4*)(Xf + idx) = o;
    }
  } else {
    int h = b - 2112;
    for (int pos = t; pos < 2048; pos += 256) {
      int kt = pos >> 8, ct = (pos >> 6) & 3, l = pos & 63;
      int lr = l & 15, lg = l >> 4;
#pragma unroll
      for (int e = 0; e < 8; ++e)
        wfrag[(size_t)(((h*8 + kt)*4 + ct)*64 + l) * 8 + e]
          = (_Float16)W[(size_t)(h*256 + kt*32 + lg*8 + e) * 64 + ct*16 + lr];
    }
  }
}

// k_hf: H = X @ W[h] (f16 MFMA) -> B-frag layout; f1/f2 from acc in epilogue
__global__ __launch_bounds__(256) void k_hf(
    const _Float16* __restrict__ Xf, const _Float16* __restrict__ wfrag,
    const float* __restrict__ a, _Float16* __restrict__ bfrag,
    float* __restrict__ f1, float* __restrict__ f2) {
  int b = blockIdx.x, t = threadIdx.x;
  int h = b & 7, rb = b >> 3;
  int w = t >> 6, l = t & 63;
  int i0 = rb * 128 + w * 32;
  int r = l & 15, g = l >> 4;
  const U4* xv = (const U4*)Xf;
  const U4* wv = (const U4*)wfrag;
  f32x4 z = {0.f, 0.f, 0.f, 0.f};
  f32x4 acc[2][4] = {{z,z,z,z},{z,z,z,z}};
#pragma unroll
  for (int kt = 0; kt < 8; ++kt) {
    U4 a0 = xv[(i0 + r) * 32 + kt*4 + g];
    U4 a1 = xv[(i0 + 16 + r) * 32 + kt*4 + g];
#pragma unroll
    for (int ct = 0; ct < 4; ++ct) {
      U4 bv = wv[((h*8 + kt)*4 + ct)*64 + l];
      acc[0][ct] = __builtin_amdgcn_mfma_f32_16x16x32_f16(a0.h, bv.h, acc[0][ct], 0, 0, 0);
      acc[1][ct] = __builtin_amdgcn_mfma_f32_16x16x32_f16(a1.h, bv.h, acc[1][ct], 0, 0, 0);
    }
  }
  // H store in B-frag layout (short4 per (rt2, ct))
#pragma unroll
  for (int rt2 = 0; rt2 < 2; ++rt2)
#pragma unroll
    for (int ct = 0; ct < 4; ++ct) {
      int jb = i0 + rt2*16 + g*4;
      size_t base = ((((size_t)h*128 + (jb>>5))*4 + ct)*64 + ((jb>>3)&3)*16 + r) * 8
                    + (jb & 7);
      union { short4 s; _Float16 hh[4]; } sv;
#pragma unroll
      for (int ri = 0; ri < 4; ++ri) sv.hh[ri] = (_Float16)acc[rt2][ct][ri];
      *(short4*)(bfrag + base) = sv.s;
    }
  // f1/f2 epilogue: f[row] = H[row,:] . a{1,2};  D col = ct*16 + r
  float a1v[4], a2v[4];
#pragma unroll
  for (int ct = 0; ct < 4; ++ct) {
    a1v[ct] = a[h*128 + ct*16 + r];
    a2v[ct] = a[h*128 + 64 + ct*16 + r];
  }
#pragma unroll
  for (int rt2 = 0; rt2 < 2; ++rt2)
#pragma unroll
    for (int ri = 0; ri < 4; ++ri) {
      float s1 = acc[rt2][0][ri]*a1v[0] + acc[rt2][1][ri]*a1v[1]
               + acc[rt2][2][ri]*a1v[2] + acc[rt2][3][ri]*a1v[3];
      float s2 = acc[rt2][0][ri]*a2v[0] + acc[rt2][1][ri]*a2v[1]
               + acc[rt2][2][ri]*a2v[2] + acc[rt2][3][ri]*a2v[3];
#pragma unroll
      for (int off = 1; off < 16; off <<= 1) {
        s1 += __shfl_xor(s1, off);
        s2 += __shfl_xor(s2, off);
      }
      if (r == 0) {
        int row = i0 + rt2*16 + g*4 + ri;
        f1[h*4096 + row] = s1;
        f2[h*4096 + row] = s2;
      }
    }
}

// k_gtab: per-head f2 max + G tables Gp=exp(f2), Gn=exp(a*f2) in f16
__global__ __launch_bounds__(256) void k_gtab(const float* __restrict__ f2,
                                              float* __restrict__ fmx,
                                              _Float16* __restrict__ Gp,
                                              _Float16* __restrict__ Gn) {
  int h = blockIdx.x, t = threadIdx.x;
  const float* f = f2 + h * 4096;
  float m = -1e30f;
  for (int i = t; i < 4096; i += 256) m = fmaxf(m, f[i]);
#pragma unroll
  for (int off = 32; off >= 1; off >>= 1) m = fmaxf(m, __shfl_xor(m, off, 64));
  __shared__ float sm[4];
  if ((t & 63) == 0) sm[t >> 6] = m;
  __syncthreads();
  if (t == 0) fmx[h] = fmaxf(fmaxf(sm[0], sm[1]), fmaxf(sm[2], sm[3]));
  for (int i = t; i < 4096; i += 256) {
    float v = f[i];
    Gp[h*4096 + i] = (_Float16)__expf(v);
    Gn[h*4096 + i] = (_Float16)__expf(ALPHA * v);
  }
}

#define ATTN_BODY(PF, JT, DOPF) {                                              \
  U4 gp, gn;                                                                   \
  gp.u = Gs[0][(JT)*4 + g].u;                                                  \
  gn.u = Gs[1][(JT)*4 + g].u;                                                  \
  U4 b0, b1, b2, b3;                                                           \
  b0.u = PF[0]; b1.u = PF[1]; b2.u = PF[2]; b3.u = PF[3];                      \
  _Pragma("unroll")                                                            \
  for (int rg = 0; rg < 4; ++rg) {                                             \
    unsigned wm = Lb[rg*16 + r][JT];                                           \
    U4 av;                                                                     \
    _Pragma("unroll")                                                          \
    for (int p = 0; p < 4; ++p) {                                              \
      unsigned pm = pkmax(pkmul(Epp[rg], gp.w[p]), pkmul(Enn[rg], gn.w[p]));   \
      int s = g8 + 2*p;                                                        \
      unsigned lo = (unsigned)((int)(wm << (31 - s)) >> 31) & 0xFFFFu;         \
      unsigned hi = (unsigned)((int)(wm << (30 - s)) >> 31) & 0xFFFF0000u;     \
      av.w[p] = pm & (lo | hi);                                                \
    }                                                                          \
    acc[rg][0] = __builtin_amdgcn_mfma_f32_16x16x32_f16(av.h, b0.h, acc[rg][0], 0,0,0); \
    acc[rg][1] = __builtin_amdgcn_mfma_f32_16x16x32_f16(av.h, b1.h, acc[rg][1], 0,0,0); \
    acc[rg][2] = __builtin_amdgcn_mfma_f32_16x16x32_f16(av.h, b2.h, acc[rg][2], 0,0,0); \
    acc[rg][3] = __builtin_amdgcn_mfma_f32_16x16x32_f16(av.h, b3.h, acc[rg][3], 0,0,0); \
    dnw[rg] = pkadd(dnw[rg], pkadd(pkadd(av.w[0], av.w[1]), pkadd(av.w[2], av.w[3]))); \
  }                                                                            \
  if (DOPF) {                                                                  \
    _Pragma("unroll")                                                          \
    for (int c = 0; c < 4; ++c) PF[c] = bfh[(size_t)((JT) + 2) * 256 + c*64];  \
  }                                                                            \
}

// k_attn v4: block=(head, 64 rows); 4 waves = 4 j-quarters; 64 rows per wave
// (4 A-frag rowgroups), private B reads with 2-jt register prefetch.
__global__ __launch_bounds__(256) void k_attn(
    const float* __restrict__ f1, const float* __restrict__ f2max,
    const unsigned int* __restrict__ adjbits, const _Float16* __restrict__ Gp,
    const _Float16* __restrict__ Gn, const _Float16* __restrict__ bfrag,
    float* __restrict__ hpart) {
  __shared__ unsigned Lb[64][129];                 // 33 KB adjacency bits
  __shared__ U4 Gs[2][512];                        // 16 KB Gp/Gn head slices
  __shared__ f32x4 red[17][64];                    // 17 KB jq-reduction buffer
  int b = blockIdx.x;
  int h = b & 7, rs = b >> 3;                      // head <-> XCD L2 locality
  int i0 = rs * 64;
  int t = threadIdx.x, jq = t >> 6, l = t & 63;
  int r = l & 15, g = l >> 4, g8 = g * 8;
  for (int q = t; q < 64 * 128; q += 256)
    Lb[q >> 7][q & 127] = adjbits[(size_t)(i0 + (q >> 7)) * 128 + (q & 127)];
  {
    const uint4* gp4 = (const uint4*)(Gp + (size_t)h * 4096);
    const uint4* gn4 = (const uint4*)(Gn + (size_t)h * 4096);
#pragma unroll
    for (int q = 0; q < 2; ++q) {
      Gs[0][q * 256 + t].u = gp4[q * 256 + t];
      Gs[1][q * 256 + t].u = gn4[q * 256 + t];
    }
  }
  float F2m = f2max[h];
  unsigned Epp[4], Enn[4];
#pragma unroll
  for (int rg = 0; rg < 4; ++rg) {
    float f1r = f1[h * N_NODES + i0 + rg*16 + r];
    float sM = f1r + F2m;
    float M = fmaxf(sM, ALPHA * sM);               // row-max upper bound
    unsigned short ep = f2h_bits(__expf(f1r - M));
    unsigned short en = f2h_bits(__expf(ALPHA * f1r - M));
    Epp[rg] = ep | ((unsigned)ep << 16);
    Enn[rg] = en | ((unsigned)en << 16);
  }
  const uint4* bfh = (const uint4*)bfrag + (size_t)h * (128 * 256) + l;
  int jt0 = jq * 32;
  uint4 pA[4], pB[4];
#pragma unroll
  for (int c = 0; c < 4; ++c) pA[c] = bfh[(size_t)jt0 * 256 + c*64];
#pragma unroll
  for (int c = 0; c < 4; ++c) pB[c] = bfh[(size_t)(jt0 + 1) * 256 + c*64];
  __syncthreads();
  f32x4 z = {0.f,0.f,0.f,0.f};
  f32x4 acc[4][4] = {{z,z,z,z},{z,z,z,z},{z,z,z,z},{z,z,z,z}};
  unsigned dnw[4] = {0u,0u,0u,0u};
  for (int q2 = 0; q2 < 16; ++q2) {
    int jt = jt0 + q2 * 2;
    ATTN_BODY(pA, jt,     (q2 < 15));
    ATTN_BODY(pB, jt + 1, (q2 < 15));
  }
  // den f16 -> f32 per rowgroup
  float den4[4];
#pragma unroll
  for (int rg = 0; rg < 4; ++rg) den4[rg] = pk_lo(dnw[rg]) + pk_hi(dnw[rg]);
  // cross-jq reduction (3 rounds)
  for (int src = 1; src < 4; ++src) {
    if (jq == src) {
#pragma unroll
      for (int rg = 0; rg < 4; ++rg)
#pragma unroll
        for (int ct = 0; ct < 4; ++ct) red[rg*4 + ct][l] = acc[rg][ct];
      f32x4 dv = {den4[0], den4[1], den4[2], den4[3]};
      red[16][l] = dv;
    }
    __syncthreads();
    if (jq == 0) {
#pragma unroll
      for (int rg = 0; rg < 4; ++rg)
#pragma unroll
        for (int ct = 0; ct < 4; ++ct) acc[rg][ct] += red[rg*4 + ct][l];
      f32x4 dv = red[16][l];
#pragma unroll
      for (int rg = 0; rg < 4; ++rg) den4[rg] += dv[rg];
    }
    __syncthreads();
  }
  if (jq == 0) {
    // den: reduce over k-slices (g groups)
#pragma unroll
    for (int rg = 0; rg < 4; ++rg) {
      den4[rg] += __shfl_xor(den4[rg], 16);
      den4[rg] += __shfl_xor(den4[rg], 32);
    }
    // normalize + store;  D: row = rg*16 + g*4 + ri, col = ct*16 + r
#pragma unroll
    for (int rg = 0; rg < 4; ++rg)
#pragma unroll
      for (int ri = 0; ri < 4; ++ri) {
        float den = __shfl(den4[rg], (l & 48) | (g*4 + ri));
        float sc = 0.125f / den;
        float* hp = hpart + ((size_t)h * N_NODES + i0 + rg*16 + g*4 + ri) * 64;
        hp[r]      = acc[rg][0][ri] * sc;
        hp[16 + r] = acc[rg][1][ri] * sc;
        hp[32 + r] = acc[rg][2][ri] * sc;
        hp[48 + r] = acc[rg][3][ri] * sc;
      }
  }
}

// out = sum_h hpart[h]  (0.125 already folded in)
__global__ __launch_bounds__(256) void k_hmean(const float* __restrict__ hpart,
                                               float* __restrict__ out) {
  int idx = blockIdx.x * 256 + threadIdx.x;
  const float4* hp = (const float4*)hpart;
  float4 s = hp[idx];
#pragma unroll
  for (int h = 1; h < 8; ++h) {
    float4 v = hp[h * 65536 + idx];
    s.x += v.x; s.y += v.y; s.z += v.z; s.w += v.w;
  }
  ((float4*)out)[idx] = s;
}

extern "C" void kernel_launch(void* const* d_in, const int* in_sizes, int n_in,
                              void* d_out, int out_size, void* d_ws, size_t ws_size,
                              hipStream_t stream) {
  const float* X = (const float*)d_in[0];
  const int* adj = (const int*)d_in[1];
  const float* W = (const float*)d_in[2];
  const float* a = (const float*)d_in[3];
  float* out = (float*)d_out;
  char* ws = (char*)d_ws;

  _Float16* Xf    = (_Float16*)(ws + XF_OFF);
  _Float16* wfrag = (_Float16*)(ws + WFRAG_OFF);
  _Float16* bfrag = (_Float16*)(ws + BFRAG_OFF);
  float* f1  = (float*)(ws + F1_OFF);
  float* f2  = (float*)(ws + F2_OFF);
  float* fmx = (float*)(ws + FMAX_OFF);
  _Float16* Gp = (_Float16*)(ws + GP_OFF);
  _Float16* Gn = (_Float16*)(ws + GN_OFF);
  unsigned long long* bits64 = (unsigned long long*)(ws + ADJ_OFF);
  const unsigned int* bits32 = (const unsigned int*)(ws + ADJ_OFF);
  float* hpart = (float*)(ws + HPART_OFF);

  k_misc<<<dim3(2120), dim3(256), 0, stream>>>(X, adj, W, Xf, bits64, wfrag);
  k_hf<<<dim3(256), dim3(256), 0, stream>>>(Xf, wfrag, a, bfrag, f1, f2);
  k_gtab<<<dim3(8), dim3(256), 0, stream>>>(f2, fmx, Gp, Gn);
  k_attn<<<dim3(512), dim3(256), 0, stream>>>(f1, fmx, bits32, Gp, Gn, bfrag, hpart);
  k_hmean<<<dim3(256), dim3(256), 0, stream>>>(hpart, out);
}

// Round 7
// 79.241 us; speedup vs baseline: 1.7134x; 1.0995x over previous
//
#include <hip/hip_runtime.h>
#include <hip/hip_bf16.h>

#define N_NODES 4096
#define IN_F 256
#define OUT_F 64
#define HEADS 8
#define ALPHA 0.2f

typedef _Float16 f16x8 __attribute__((ext_vector_type(8)));
typedef float f32x4 __attribute__((ext_vector_type(4)));
union U4 { uint4 u; f16x8 h; unsigned w[4]; };

// ---- workspace layout (bytes) ----
#define WFRAG_OFF 0                                 // 256 KB f16 W B-frags
#define BFRAG_OFF (WFRAG_OFF + 8*8*4*64*8*2)        // 4 MB  f16 H B-frags
#define F1_OFF    (BFRAG_OFF + 8*128*4*64*8*2)      // 128 KB f32 f1
#define GP_OFF    (F1_OFF + 8*4096*4)               // 64 KB f16 exp(f2)
#define GN_OFF    (GP_OFF + 8*4096*2)               // 64 KB f16 exp(a*f2)
#define ADJ_OFF   (GN_OFF + 8*4096*2)               // 2 MB adjacency bitmask

static __device__ __forceinline__ unsigned pkmul(unsigned a, unsigned b) {
  unsigned r; asm("v_pk_mul_f16 %0, %1, %2" : "=v"(r) : "v"(a), "v"(b)); return r;
}
static __device__ __forceinline__ unsigned pkmax(unsigned a, unsigned b) {
  unsigned r; asm("v_pk_max_f16 %0, %1, %2" : "=v"(r) : "v"(a), "v"(b)); return r;
}
static __device__ __forceinline__ unsigned short f2h_bits(float f) {
  return __builtin_bit_cast(unsigned short, (_Float16)f);
}

// k_misc: [0,2048) adj->bitmask; [2048,2056) W B-frags + zero out
__global__ __launch_bounds__(256) void k_misc(
    const int* __restrict__ adj, const float* __restrict__ W,
    unsigned long long* __restrict__ bits, _Float16* __restrict__ wfrag,
    float* __restrict__ out) {
  int b = blockIdx.x, t = threadIdx.x;
  if (b < 2048) {
    int lane = t & 63;
    int waveid = b * 4 + (t >> 6);
    for (int it = 0; it < 32; ++it) {
      int widx = waveid + it * 8192;
      int v = adj[(size_t)widx * 64 + lane];
      unsigned long long m = __ballot(v != 0);
      if (lane == 0) bits[widx] = m;
    }
  } else {
    int h = b - 2048;
    for (int pos = t; pos < 2048; pos += 256) {
      int kt = pos >> 8, ct = (pos >> 6) & 3, l = pos & 63;
      int lr = l & 15, lg = l >> 4;
#pragma unroll
      for (int e = 0; e < 8; ++e)
        wfrag[(size_t)(((h*8 + kt)*4 + ct)*64 + l) * 8 + e]
          = (_Float16)W[(size_t)(h*256 + kt*32 + lg*8 + e) * 64 + ct*16 + lr];
    }
    float4* oz = ((float4*)out) + h * 8192;
    float4 zz = make_float4(0.f, 0.f, 0.f, 0.f);
    for (int q = t; q < 8192; q += 256) oz[q] = zz;
  }
}

// k_hf: H = X @ W[h] (f16 MFMA, X converted in-register) -> B-frag layout;
// epilogue: f1 = H.a1 (f32), Gp = exp(H.a2), Gn = exp(a*H.a2)
__global__ __launch_bounds__(256) void k_hf(
    const float* __restrict__ X, const _Float16* __restrict__ wfrag,
    const float* __restrict__ a, _Float16* __restrict__ bfrag,
    float* __restrict__ f1, _Float16* __restrict__ Gp, _Float16* __restrict__ Gn) {
  int b = blockIdx.x, t = threadIdx.x;
  int h = b & 7, rb = b >> 3;                      // rb 0..63, 64 rows/block
  int w = t >> 6, l = t & 63;
  int i0 = rb * 64 + w * 16;                       // 16 rows per wave
  int r = l & 15, g = l >> 4;
  const U4* wv = (const U4*)wfrag;
  f32x4 z = {0.f, 0.f, 0.f, 0.f};
  f32x4 acc[4] = {z, z, z, z};
#pragma unroll
  for (int kt = 0; kt < 8; ++kt) {
    const float4* xr = (const float4*)(X + (size_t)(i0 + r) * 256 + (kt*4 + g) * 8);
    float4 x0 = xr[0], x1 = xr[1];
    U4 af;
    af.h[0] = (_Float16)x0.x; af.h[1] = (_Float16)x0.y;
    af.h[2] = (_Float16)x0.z; af.h[3] = (_Float16)x0.w;
    af.h[4] = (_Float16)x1.x; af.h[5] = (_Float16)x1.y;
    af.h[6] = (_Float16)x1.z; af.h[7] = (_Float16)x1.w;
#pragma unroll
    for (int ct = 0; ct < 4; ++ct) {
      U4 bv = wv[((h*8 + kt)*4 + ct)*64 + l];
      acc[ct] = __builtin_amdgcn_mfma_f32_16x16x32_f16(af.h, bv.h, acc[ct], 0, 0, 0);
    }
  }
  // H store in B-frag layout
  int jb = i0 + g*4;
#pragma unroll
  for (int ct = 0; ct < 4; ++ct) {
    size_t base = ((((size_t)h*128 + (jb>>5))*4 + ct)*64 + ((jb>>3)&3)*16 + r) * 8
                  + (jb & 7);
    union { short4 s; _Float16 hh[4]; } sv;
#pragma unroll
    for (int ri = 0; ri < 4; ++ri) sv.hh[ri] = (_Float16)acc[ct][ri];
    *(short4*)(bfrag + base) = sv.s;
  }
  // f1/G epilogue
  float a1v[4], a2v[4];
#pragma unroll
  for (int ct = 0; ct < 4; ++ct) {
    a1v[ct] = a[h*128 + ct*16 + r];
    a2v[ct] = a[h*128 + 64 + ct*16 + r];
  }
#pragma unroll
  for (int ri = 0; ri < 4; ++ri) {
    float s1 = acc[0][ri]*a1v[0] + acc[1][ri]*a1v[1]
             + acc[2][ri]*a1v[2] + acc[3][ri]*a1v[3];
    float s2 = acc[0][ri]*a2v[0] + acc[1][ri]*a2v[1]
             + acc[2][ri]*a2v[2] + acc[3][ri]*a2v[3];
#pragma unroll
    for (int off = 1; off < 16; off <<= 1) {
      s1 += __shfl_xor(s1, off);
      s2 += __shfl_xor(s2, off);
    }
    if (r == 0) {
      int row = i0 + g*4 + ri;
      f1[h*4096 + row] = s1;
      Gp[h*4096 + row] = (_Float16)__expf(s2);
      Gn[h*4096 + row] = (_Float16)__expf(ALPHA * s2);
    }
  }
}

#define ATTN_BODY(PF, JT, DOPF) {                                              \
  U4 gp, gn;                                                                   \
  gp.u = Gs[0][(JT)*4 + g].u;                                                  \
  gn.u = Gs[1][(JT)*4 + g].u;                                                  \
  U4 b0, b1, b2, b3;                                                           \
  b0.u = PF[0]; b1.u = PF[1]; b2.u = PF[2]; b3.u = PF[3];                      \
  _Pragma("unroll")                                                            \
  for (int rg = 0; rg < 4; ++rg) {                                             \
    unsigned wm = Lb[rg*16 + r][JT];                                           \
    U4 av;                                                                     \
    _Pragma("unroll")                                                          \
    for (int p = 0; p < 4; ++p) {                                              \
      unsigned pm = pkmax(pkmul(Epp[rg], gp.w[p]), pkmul(Enn[rg], gn.w[p]));   \
      av.w[p] = pm & MLUT[(wm >> (g8 + 2*p)) & 3u];                            \
    }                                                                          \
    acc[rg][0] = __builtin_amdgcn_mfma_f32_16x16x32_f16(av.h, b0.h, acc[rg][0], 0,0,0); \
    acc[rg][1] = __builtin_amdgcn_mfma_f32_16x16x32_f16(av.h, b1.h, acc[rg][1], 0,0,0); \
    acc[rg][2] = __builtin_amdgcn_mfma_f32_16x16x32_f16(av.h, b2.h, acc[rg][2], 0,0,0); \
    acc[rg][3] = __builtin_amdgcn_mfma_f32_16x16x32_f16(av.h, b3.h, acc[rg][3], 0,0,0); \
    dn[rg]     = __builtin_amdgcn_mfma_f32_16x16x32_f16(av.h, bones.h, dn[rg], 0,0,0);  \
  }                                                                            \
  if (DOPF) {                                                                  \
    _Pragma("unroll")                                                          \
    for (int c = 0; c < 4; ++c) PF[c] = bfh[((JT) + 2)*256 + c*64];            \
  }                                                                            \
}

#define WRBUF(buf) {                                                           \
  _Pragma("unroll")                                                            \
  for (int rg = 0; rg < 4; ++rg) {                                             \
    _Pragma("unroll")                                                          \
    for (int ct = 0; ct < 4; ++ct) buf[rg*4 + ct][l] = acc[rg][ct];            \
    buf[16 + rg][l] = dn[rg];                                                  \
  } }
#define ADBUF(buf) {                                                           \
  _Pragma("unroll")                                                            \
  for (int rg = 0; rg < 4; ++rg) {                                             \
    _Pragma("unroll")                                                          \
    for (int ct = 0; ct < 4; ++ct) acc[rg][ct] += buf[rg*4 + ct][l];           \
    dn[rg] += buf[16 + rg][l];                                                 \
  } }

// k_attn v5: block=(head, 64 rows) x 512 thr; 8 waves = 8 j-eighths (16 jt).
// No max-shift (scores bounded); mask via 4-entry LDS LUT; den via ones-MFMA;
// atomicAdd head-mean into out. LDS 49.4 KB -> 16 waves/CU.
__global__ __launch_bounds__(512) void k_attn(
    const float* __restrict__ f1, const unsigned int* __restrict__ adjbits,
    const _Float16* __restrict__ Gp, const _Float16* __restrict__ Gn,
    const _Float16* __restrict__ bfrag, float* __restrict__ out) {
  __shared__ __align__(16) char smem[49408];
  __shared__ unsigned MLUT[4];
  unsigned (*Lb)[129] = (unsigned(*)[129])smem;    // 33024 B
  U4 (*Gs)[512] = (U4(*)[512])(smem + 33024);      // 16384 B
  f32x4 (*red0)[64] = (f32x4(*)[64])smem;          // overlays after main loop
  f32x4 (*red1)[64] = (f32x4(*)[64])(smem + 20480);
  int b = blockIdx.x;
  int h = b & 7, rs = b >> 3;                      // head <-> XCD L2 locality
  int i0 = rs * 64;
  int t = threadIdx.x, jq = t >> 6, l = t & 63;
  int r = l & 15, g = l >> 4, g8 = g * 8;
  if (t < 4) MLUT[t] = ((t & 1) ? 0xFFFFu : 0u) | ((t & 2) ? 0xFFFF0000u : 0u);
  for (int q = t; q < 8192; q += 512)
    Lb[q >> 7][q & 127] = adjbits[(size_t)(i0 + (q >> 7)) * 128 + (q & 127)];
  Gs[0][t].u = ((const uint4*)(Gp + (size_t)h * 4096))[t];
  Gs[1][t].u = ((const uint4*)(Gn + (size_t)h * 4096))[t];
  unsigned Epp[4], Enn[4];
#pragma unroll
  for (int rg = 0; rg < 4; ++rg) {
    float f1r = f1[h * N_NODES + i0 + rg*16 + r];
    unsigned short ep = f2h_bits(__expf(f1r));
    unsigned short en = f2h_bits(__expf(ALPHA * f1r));
    Epp[rg] = ep | ((unsigned)ep << 16);
    Enn[rg] = en | ((unsigned)en << 16);
  }
  unsigned ov = (r == 0) ? 0x3C003C00u : 0u;       // ones column B-frag (f16 1.0)
  U4 bones; bones.u = make_uint4(ov, ov, ov, ov);
  const uint4* bfh = (const uint4*)bfrag + (size_t)h * 32768 + l;
  int jt0 = jq * 16;
  uint4 pA[4], pB[4];
#pragma unroll
  for (int c = 0; c < 4; ++c) pA[c] = bfh[jt0 * 256 + c*64];
#pragma unroll
  for (int c = 0; c < 4; ++c) pB[c] = bfh[(jt0 + 1) * 256 + c*64];
  __syncthreads();
  f32x4 z = {0.f,0.f,0.f,0.f};
  f32x4 acc[4][4] = {{z,z,z,z},{z,z,z,z},{z,z,z,z},{z,z,z,z}};
  f32x4 dn[4] = {z,z,z,z};
  for (int q2 = 0; q2 < 8; ++q2) {
    ATTN_BODY(pA, jt0 + q2*2,     (q2 < 7));
    ATTN_BODY(pB, jt0 + q2*2 + 1, (q2 < 7));
  }
  __syncthreads();                                 // Lb/Gs dead; red overlays
  // cross-jq tree reduction (2 buffers, 4 rounds)
  if (jq == 1) WRBUF(red0);
  if (jq == 5) WRBUF(red1);
  __syncthreads();
  if (jq == 0) ADBUF(red0);
  if (jq == 4) ADBUF(red1);
  __syncthreads();
  if (jq == 3) WRBUF(red0);
  if (jq == 7) WRBUF(red1);
  __syncthreads();
  if (jq == 2) ADBUF(red0);
  if (jq == 6) ADBUF(red1);
  __syncthreads();
  if (jq == 2) WRBUF(red0);
  if (jq == 6) WRBUF(red1);
  __syncthreads();
  if (jq == 0) ADBUF(red0);
  if (jq == 4) ADBUF(red1);
  __syncthreads();
  if (jq == 4) WRBUF(red0);
  __syncthreads();
  if (jq == 0) {
    ADBUF(red0);
#pragma unroll
    for (int rg = 0; rg < 4; ++rg)
#pragma unroll
      for (int ri = 0; ri < 4; ++ri) {
        float den = __shfl(dn[rg][ri], l & 48);    // D col 0 holds row-sum
        float sc = 0.125f / den;
        float* op = out + (size_t)(i0 + rg*16 + g*4 + ri) * 64;
        atomicAdd(op + r,      acc[rg][0][ri] * sc);
        atomicAdd(op + 16 + r, acc[rg][1][ri] * sc);
        atomicAdd(op + 32 + r, acc[rg][2][ri] * sc);
        atomicAdd(op + 48 + r, acc[rg][3][ri] * sc);
      }
  }
}

extern "C" void kernel_launch(void* const* d_in, const int* in_sizes, int n_in,
                              void* d_out, int out_size, void* d_ws, size_t ws_size,
                              hipStream_t stream) {
  const float* X = (const float*)d_in[0];
  const int* adj = (const int*)d_in[1];
  const float* W = (const float*)d_in[2];
  const float* a = (const float*)d_in[3];
  float* out = (float*)d_out;
  char* ws = (char*)d_ws;

  _Float16* wfrag = (_Float16*)(ws + WFRAG_OFF);
  _Float16* bfrag = (_Float16*)(ws + BFRAG_OFF);
  float* f1 = (float*)(ws + F1_OFF);
  _Float16* Gp = (_Float16*)(ws + GP_OFF);
  _Float16* Gn = (_Float16*)(ws + GN_OFF);
  unsigned long long* bits64 = (unsigned long long*)(ws + ADJ_OFF);
  const unsigned int* bits32 = (const unsigned int*)(ws + ADJ_OFF);

  k_misc<<<dim3(2056), dim3(256), 0, stream>>>(adj, W, bits64, wfrag, out);
  k_hf<<<dim3(512), dim3(256), 0, stream>>>(X, wfrag, a, bfrag, f1, Gp, Gn);
  k_attn<<<dim3(512), dim3(512), 0, stream>>>(f1, bits32, Gp, Gn, bfrag, out);
}

// Round 8
// 77.780 us; speedup vs baseline: 1.7456x; 1.0188x over previous
//
#include <hip/hip_runtime.h>
#include <hip/hip_bf16.h>

#define N_NODES 4096
#define IN_F 256
#define OUT_F 64
#define HEADS 8
#define ALPHA 0.2f

typedef _Float16 f16x8 __attribute__((ext_vector_type(8)));
typedef float f32x4 __attribute__((ext_vector_type(4)));
union U4 { uint4 u; f16x8 h; unsigned w[4]; };

// ---- workspace layout (bytes) ----
#define BFRAG_OFF 0                                 // 4 MB  f16 H B-frags
#define F1_OFF    (BFRAG_OFF + 8*128*4*64*8*2)      // 128 KB f32 f1
#define GP_OFF    (F1_OFF + 8*4096*4)               // 64 KB f16 exp(f2)
#define GN_OFF    (GP_OFF + 8*4096*2)               // 64 KB f16 exp(a*f2)
#define ADJ_OFF   (GN_OFF + 8*4096*2)               // 2 MB adjacency bitmask

static __device__ __forceinline__ unsigned pkmul(unsigned a, unsigned b) {
  unsigned r; asm("v_pk_mul_f16 %0, %1, %2" : "=v"(r) : "v"(a), "v"(b)); return r;
}
static __device__ __forceinline__ unsigned pkmax(unsigned a, unsigned b) {
  unsigned r; asm("v_pk_max_f16 %0, %1, %2" : "=v"(r) : "v"(a), "v"(b)); return r;
}
static __device__ __forceinline__ unsigned pkadd(unsigned a, unsigned b) {
  unsigned r; asm("v_pk_add_f16 %0, %1, %2" : "=v"(r) : "v"(a), "v"(b)); return r;
}
static __device__ __forceinline__ unsigned short f2h_bits(float f) {
  return __builtin_bit_cast(unsigned short, (_Float16)f);
}
static __device__ __forceinline__ float h2f(unsigned short x) {
  return (float)__builtin_bit_cast(_Float16, x);
}

// k_all: [0,2048) adj->bitmask; [2048,2560) per-head-rowblock H GEMM:
//   W[h]->LDS frags, H=X@W via MFMA -> bfrag; f1/Gp/Gn epilogue; h==0 zeros out
__global__ __launch_bounds__(256) void k_all(
    const float* __restrict__ X, const int* __restrict__ adj,
    const float* __restrict__ W, const float* __restrict__ a,
    unsigned long long* __restrict__ bits, _Float16* __restrict__ bfrag,
    float* __restrict__ f1, _Float16* __restrict__ Gp, _Float16* __restrict__ Gn,
    float* __restrict__ out) {
  __shared__ _Float16 wf[16384];                   // 32 KB W[h] B-frags
  int b = blockIdx.x, t = threadIdx.x;
  if (b < 2048) {
    int lane = t & 63;
    int waveid = b * 4 + (t >> 6);
    for (int it = 0; it < 32; ++it) {
      int widx = waveid + it * 8192;
      int v = adj[(size_t)widx * 64 + lane];
      unsigned long long m = __ballot(v != 0);
      if (lane == 0) bits[widx] = m;
    }
    return;
  }
  int b2 = b - 2048;
  int h = b2 >> 6, rb = b2 & 63;
  // --- W[h] -> LDS fragment layout (coalesced f32 read, scattered f16 write) ---
  const float* Wh = W + (size_t)h * 16384;
  for (int q = t; q < 16384; q += 256) {
    float wv = Wh[q];
    int k = q >> 6, f = q & 63;
    int kt = k >> 5, lg = (k >> 3) & 3, e = k & 7;
    int ct = f >> 4, lr = f & 15;
    wf[(size_t)(((kt*4 + ct)*64) + lg*16 + lr) * 8 + e] = (_Float16)wv;
  }
  __syncthreads();
  int w = t >> 6, l = t & 63;
  int i0 = rb * 64 + w * 16;                       // 16 rows per wave
  int r = l & 15, g = l >> 4;
  f32x4 z = {0.f, 0.f, 0.f, 0.f};
  f32x4 acc[4] = {z, z, z, z};
#pragma unroll
  for (int kt = 0; kt < 8; ++kt) {
    const float4* xr = (const float4*)(X + (size_t)(i0 + r) * 256 + (kt*4 + g) * 8);
    float4 x0 = xr[0], x1 = xr[1];
    U4 af;
    af.h[0] = (_Float16)x0.x; af.h[1] = (_Float16)x0.y;
    af.h[2] = (_Float16)x0.z; af.h[3] = (_Float16)x0.w;
    af.h[4] = (_Float16)x1.x; af.h[5] = (_Float16)x1.y;
    af.h[6] = (_Float16)x1.z; af.h[7] = (_Float16)x1.w;
#pragma unroll
    for (int ct = 0; ct < 4; ++ct) {
      U4 bv = *(const U4*)(wf + (size_t)(((kt*4 + ct)*64) + l) * 8);
      acc[ct] = __builtin_amdgcn_mfma_f32_16x16x32_f16(af.h, bv.h, acc[ct], 0, 0, 0);
    }
  }
  // H store in B-frag layout
  int jb = i0 + g*4;
#pragma unroll
  for (int ct = 0; ct < 4; ++ct) {
    size_t base = ((((size_t)h*128 + (jb>>5))*4 + ct)*64 + ((jb>>3)&3)*16 + r) * 8
                  + (jb & 7);
    union { short4 s; _Float16 hh[4]; } sv;
#pragma unroll
    for (int ri = 0; ri < 4; ++ri) sv.hh[ri] = (_Float16)acc[ct][ri];
    *(short4*)(bfrag + base) = sv.s;
  }
  // f1/G epilogue
  float a1v[4], a2v[4];
#pragma unroll
  for (int ct = 0; ct < 4; ++ct) {
    a1v[ct] = a[h*128 + ct*16 + r];
    a2v[ct] = a[h*128 + 64 + ct*16 + r];
  }
#pragma unroll
  for (int ri = 0; ri < 4; ++ri) {
    float s1 = acc[0][ri]*a1v[0] + acc[1][ri]*a1v[1]
             + acc[2][ri]*a1v[2] + acc[3][ri]*a1v[3];
    float s2 = acc[0][ri]*a2v[0] + acc[1][ri]*a2v[1]
             + acc[2][ri]*a2v[2] + acc[3][ri]*a2v[3];
#pragma unroll
    for (int off = 1; off < 16; off <<= 1) {
      s1 += __shfl_xor(s1, off);
      s2 += __shfl_xor(s2, off);
    }
    if (r == 0) {
      int row = i0 + g*4 + ri;
      f1[h*4096 + row] = s1;
      Gp[h*4096 + row] = (_Float16)__expf(s2);
      Gn[h*4096 + row] = (_Float16)__expf(ALPHA * s2);
    }
  }
  if (h == 0) {                                    // zero 64-row out slice
    float4* oz = (float4*)(out + (size_t)(rb * 64) * 64);
    float4 zz = make_float4(0.f, 0.f, 0.f, 0.f);
    for (int q = t; q < 1024; q += 256) oz[q] = zz;
  }
}

#define ATTN_BODY(PF, JT, DOPF) {                                              \
  U4 gp, gn;                                                                   \
  gp.u = Gs0[(JT)*4 + g].u;                                                    \
  gn.u = Gs1[(JT)*4 + g].u;                                                    \
  U4 b0, b1, b2, b3;                                                           \
  b0.u = PF[0]; b1.u = PF[1]; b2.u = PF[2]; b3.u = PF[3];                      \
  _Pragma("unroll")                                                            \
  for (int rg = 0; rg < 2; ++rg) {                                             \
    unsigned wm = Lb[rh32 + rg*16 + r][JT];                                    \
    U4 av;                                                                     \
    _Pragma("unroll")                                                          \
    for (int p = 0; p < 4; ++p) {                                              \
      unsigned pm = pkmax(pkmul(Epp[rg], gp.w[p]), pkmul(Enn[rg], gn.w[p]));   \
      av.w[p] = pm & MLUT[(wm >> (g8 + 2*p)) & 3u];                            \
    }                                                                          \
    acc[rg][0] = __builtin_amdgcn_mfma_f32_16x16x32_f16(av.h, b0.h, acc[rg][0], 0,0,0); \
    acc[rg][1] = __builtin_amdgcn_mfma_f32_16x16x32_f16(av.h, b1.h, acc[rg][1], 0,0,0); \
    acc[rg][2] = __builtin_amdgcn_mfma_f32_16x16x32_f16(av.h, b2.h, acc[rg][2], 0,0,0); \
    acc[rg][3] = __builtin_amdgcn_mfma_f32_16x16x32_f16(av.h, b3.h, acc[rg][3], 0,0,0); \
    unsigned sden = pkadd(pkadd(av.w[0], av.w[1]), pkadd(av.w[2], av.w[3]));   \
    den[rg] += h2f((unsigned short)(sden & 0xFFFFu))                           \
             + h2f((unsigned short)(sden >> 16));                              \
  }                                                                            \
  if (DOPF) {                                                                  \
    _Pragma("unroll")                                                          \
    for (int c = 0; c < 4; ++c) PF[c] = bfh[((JT) + 2)*256 + c*64];            \
  }                                                                            \
}

#define WRBUF(i) {                                                             \
  _Pragma("unroll")                                                            \
  for (int rg = 0; rg < 2; ++rg)                                               \
    _Pragma("unroll")                                                          \
    for (int ct = 0; ct < 4; ++ct) redp[(i)*576 + (rg*4+ct)*64 + l] = acc[rg][ct]; \
  f32x4 dv = {den[0], den[1], 0.f, 0.f};                                       \
  redp[(i)*576 + 512 + l] = dv;                                                \
}
#define ADBUF(i) {                                                             \
  _Pragma("unroll")                                                            \
  for (int rg = 0; rg < 2; ++rg)                                               \
    _Pragma("unroll")                                                          \
    for (int ct = 0; ct < 4; ++ct) acc[rg][ct] += redp[(i)*576 + (rg*4+ct)*64 + l]; \
  f32x4 dv = redp[(i)*576 + 512 + l];                                          \
  den[0] += dv[0]; den[1] += dv[1];                                            \
}

// k_attn v6: block=(head, 64 rows) x 512 thr; 8 waves = 2 row-halves x 4 jq.
// 32 rows/wave -> ~105 regs -> 4 waves/SIMD. 2-deep private B prefetch.
__global__ __launch_bounds__(512, 4) void k_attn(
    const float* __restrict__ f1, const unsigned int* __restrict__ adjbits,
    const _Float16* __restrict__ Gp, const _Float16* __restrict__ Gn,
    const _Float16* __restrict__ bfrag, float* __restrict__ out) {
  __shared__ __align__(16) char smem[49408];
  __shared__ unsigned MLUT[4];
  unsigned (*Lb)[129] = (unsigned(*)[129])smem;    // 33024 B adjacency bits
  U4* Gs0 = (U4*)(smem + 33024);                   // 8 KB exp(f2)
  U4* Gs1 = (U4*)(smem + 41216);                   // 8 KB exp(a*f2)
  f32x4* redp = (f32x4*)smem;                      // overlay after main loop
  int b = blockIdx.x;
  int h = b & 7, rs = b >> 3;                      // head <-> XCD L2 locality
  int i0 = rs * 64;
  int t = threadIdx.x, wid = t >> 6, l = t & 63;
  int rh = wid >> 2, jq = wid & 3;
  int rh32 = rh * 32;
  int r = l & 15, g = l >> 4, g8 = g * 8;
  if (t < 4) MLUT[t] = ((t & 1) ? 0xFFFFu : 0u) | ((t & 2) ? 0xFFFF0000u : 0u);
  // B prefetch issued before staging (latency hidden under LDS fills)
  const uint4* bfh = (const uint4*)bfrag + (size_t)h * 32768 + l;
  int jt0 = jq * 32;
  uint4 pA[4], pB[4];
#pragma unroll
  for (int c = 0; c < 4; ++c) pA[c] = bfh[jt0 * 256 + c*64];
#pragma unroll
  for (int c = 0; c < 4; ++c) pB[c] = bfh[(jt0 + 1) * 256 + c*64];
  for (int q = t; q < 8192; q += 512)
    Lb[q >> 7][q & 127] = adjbits[(size_t)(i0 + (q >> 7)) * 128 + (q & 127)];
  Gs0[t].u = ((const uint4*)(Gp + (size_t)h * 4096))[t];
  Gs1[t].u = ((const uint4*)(Gn + (size_t)h * 4096))[t];
  unsigned Epp[2], Enn[2];
#pragma unroll
  for (int rg = 0; rg < 2; ++rg) {
    float f1r = f1[h * N_NODES + i0 + rh32 + rg*16 + r];
    unsigned short ep = f2h_bits(__expf(f1r));
    unsigned short en = f2h_bits(__expf(ALPHA * f1r));
    Epp[rg] = ep | ((unsigned)ep << 16);
    Enn[rg] = en | ((unsigned)en << 16);
  }
  __syncthreads();
  f32x4 z = {0.f,0.f,0.f,0.f};
  f32x4 acc[2][4] = {{z,z,z,z},{z,z,z,z}};
  float den[2] = {0.f, 0.f};
  for (int q2 = 0; q2 < 16; ++q2) {
    ATTN_BODY(pA, jt0 + q2*2,     (q2 < 15));
    ATTN_BODY(pB, jt0 + q2*2 + 1, (q2 < 15));
  }
  __syncthreads();                                 // Lb/Gs dead; redp overlays
  // cross-jq tree: (jq1,jq3)->bufs, (jq0,jq2) add; jq2->buf, jq0 adds
  if (jq == 1 || jq == 3) WRBUF(rh*2 + (jq >> 1));
  __syncthreads();
  if (jq == 0) ADBUF(rh*2);
  if (jq == 2) ADBUF(rh*2 + 1);
  __syncthreads();
  if (jq == 2) WRBUF(rh);
  __syncthreads();
  if (jq == 0) {
    ADBUF(rh);
#pragma unroll
    for (int rg = 0; rg < 2; ++rg) {
      den[rg] += __shfl_xor(den[rg], 16);
      den[rg] += __shfl_xor(den[rg], 32);          // all lanes: den of row l&15
    }
#pragma unroll
    for (int rg = 0; rg < 2; ++rg)
#pragma unroll
      for (int ri = 0; ri < 4; ++ri) {
        float dr = __shfl(den[rg], g*4 + ri);      // lane g*4+ri holds that row
        float sc = 0.125f / dr;
        float* op = out + (size_t)(i0 + rh32 + rg*16 + g*4 + ri) * 64;
        atomicAdd(op + r,      acc[rg][0][ri] * sc);
        atomicAdd(op + 16 + r, acc[rg][1][ri] * sc);
        atomicAdd(op + 32 + r, acc[rg][2][ri] * sc);
        atomicAdd(op + 48 + r, acc[rg][3][ri] * sc);
      }
  }
}

extern "C" void kernel_launch(void* const* d_in, const int* in_sizes, int n_in,
                              void* d_out, int out_size, void* d_ws, size_t ws_size,
                              hipStream_t stream) {
  const float* X = (const float*)d_in[0];
  const int* adj = (const int*)d_in[1];
  const float* W = (const float*)d_in[2];
  const float* a = (const float*)d_in[3];
  float* out = (float*)d_out;
  char* ws = (char*)d_ws;

  _Float16* bfrag = (_Float16*)(ws + BFRAG_OFF);
  float* f1 = (float*)(ws + F1_OFF);
  _Float16* Gp = (_Float16*)(ws + GP_OFF);
  _Float16* Gn = (_Float16*)(ws + GN_OFF);
  unsigned long long* bits64 = (unsigned long long*)(ws + ADJ_OFF);
  const unsigned int* bits32 = (const unsigned int*)(ws + ADJ_OFF);

  k_all<<<dim3(2560), dim3(256), 0, stream>>>(X, adj, W, a, bits64, bfrag,
                                              f1, Gp, Gn, out);
  k_attn<<<dim3(512), dim3(512), 0, stream>>>(f1, bits32, Gp, Gn, bfrag, out);
}

// Round 10
// 74.695 us; speedup vs baseline: 1.8177x; 1.0413x over previous
//
#include <hip/hip_runtime.h>
#include <hip/hip_bf16.h>

#define N_NODES 4096
#define IN_F 256
#define OUT_F 64
#define HEADS 8
#define ALPHA 0.2f

typedef _Float16 f16x8 __attribute__((ext_vector_type(8)));
typedef float f32x4 __attribute__((ext_vector_type(4)));
union U4 { uint4 u; f16x8 h; unsigned w[4]; };

// ---- workspace layout (bytes) ----
#define WFRAG_OFF 0                                 // 256 KB f16 W B-frags
#define BFRAG_OFF (WFRAG_OFF + 8*8*4*64*8*2)        // 4 MB  f16 H B-frags
#define F1_OFF    (BFRAG_OFF + 8*128*4*64*8*2)      // 128 KB f32 f1
#define GP_OFF    (F1_OFF + 8*4096*4)               // 64 KB f16 exp(f2)
#define GN_OFF    (GP_OFF + 8*4096*2)               // 64 KB f16 exp(a*f2)
#define ADJ_OFF   (GN_OFF + 8*4096*2)               // 2 MB adjacency bitmask

static __device__ __forceinline__ unsigned pkmul(unsigned a, unsigned b) {
  unsigned r; asm("v_pk_mul_f16 %0, %1, %2" : "=v"(r) : "v"(a), "v"(b)); return r;
}
static __device__ __forceinline__ unsigned pkmax(unsigned a, unsigned b) {
  unsigned r; asm("v_pk_max_f16 %0, %1, %2" : "=v"(r) : "v"(a), "v"(b)); return r;
}
static __device__ __forceinline__ unsigned pkadd(unsigned a, unsigned b) {
  unsigned r; asm("v_pk_add_f16 %0, %1, %2" : "=v"(r) : "v"(a), "v"(b)); return r;
}
static __device__ __forceinline__ unsigned short f2h_bits(float f) {
  return __builtin_bit_cast(unsigned short, (_Float16)f);
}
static __device__ __forceinline__ float h2f(unsigned short x) {
  return (float)__builtin_bit_cast(_Float16, x);
}

// k_pre: [0,8) W -> B-frag layout; [8,16) zero out
__global__ __launch_bounds__(256) void k_pre(const float* __restrict__ W,
                                             _Float16* __restrict__ wfrag,
                                             float* __restrict__ out) {
  int b = blockIdx.x, t = threadIdx.x;
  if (b < 8) {
    int h = b;
    for (int pos = t; pos < 2048; pos += 256) {
      int kt = pos >> 8, ct = (pos >> 6) & 3, l = pos & 63;
      int lr = l & 15, lg = l >> 4;
#pragma unroll
      for (int e = 0; e < 8; ++e)
        wfrag[(size_t)(((h*8 + kt)*4 + ct)*64 + l) * 8 + e]
          = (_Float16)W[(size_t)(h*256 + kt*32 + lg*8 + e) * 64 + ct*16 + lr];
    }
  } else {
    float4* oz = ((float4*)out) + (size_t)(b - 8) * 8192;
    float4 zz = make_float4(0.f, 0.f, 0.f, 0.f);
    for (int q = t; q < 8192; q += 256) oz[q] = zz;
  }
}

// k_main: [0,512) H=X@W (f16 MFMA, no LDS) + f1/Gp/Gn epilogue;
//         [512,2560) adj->bitmask, unroll x4, nontemporal loads
__global__ __launch_bounds__(256) void k_main(
    const float* __restrict__ X, const int* __restrict__ adj,
    const _Float16* __restrict__ wfrag, const float* __restrict__ a,
    unsigned long long* __restrict__ bits, _Float16* __restrict__ bfrag,
    float* __restrict__ f1, _Float16* __restrict__ Gp, _Float16* __restrict__ Gn) {
  int b = blockIdx.x, t = threadIdx.x;
  if (b >= 512) {
    int b2 = b - 512;
    int lane = t & 63;
    int waveid = b2 * 4 + (t >> 6);
#pragma unroll
    for (int it2 = 0; it2 < 8; ++it2) {
      int w0 = waveid + (it2*4 + 0) * 8192;
      int w1 = waveid + (it2*4 + 1) * 8192;
      int w2 = waveid + (it2*4 + 2) * 8192;
      int w3 = waveid + (it2*4 + 3) * 8192;
      int v0 = __builtin_nontemporal_load(adj + (size_t)w0 * 64 + lane);
      int v1 = __builtin_nontemporal_load(adj + (size_t)w1 * 64 + lane);
      int v2 = __builtin_nontemporal_load(adj + (size_t)w2 * 64 + lane);
      int v3 = __builtin_nontemporal_load(adj + (size_t)w3 * 64 + lane);
      unsigned long long m0 = __ballot(v0 != 0);
      unsigned long long m1 = __ballot(v1 != 0);
      unsigned long long m2 = __ballot(v2 != 0);
      unsigned long long m3 = __ballot(v3 != 0);
      if (lane == 0) { bits[w0] = m0; bits[w1] = m1; bits[w2] = m2; bits[w3] = m3; }
    }
    return;
  }
  int h = b & 7, rb = b >> 3;
  int w = t >> 6, l = t & 63;
  int i0 = rb * 64 + w * 16;                       // 16 rows per wave
  int r = l & 15, g = l >> 4;
  const U4* wv = (const U4*)wfrag;
  f32x4 z = {0.f, 0.f, 0.f, 0.f};
  f32x4 acc[4] = {z, z, z, z};
#pragma unroll
  for (int kt = 0; kt < 8; ++kt) {
    const float4* xr = (const float4*)(X + (size_t)(i0 + r) * 256 + (kt*4 + g) * 8);
    float4 x0 = xr[0], x1 = xr[1];
    U4 af;
    af.h[0] = (_Float16)x0.x; af.h[1] = (_Float16)x0.y;
    af.h[2] = (_Float16)x0.z; af.h[3] = (_Float16)x0.w;
    af.h[4] = (_Float16)x1.x; af.h[5] = (_Float16)x1.y;
    af.h[6] = (_Float16)x1.z; af.h[7] = (_Float16)x1.w;
#pragma unroll
    for (int ct = 0; ct < 4; ++ct) {
      U4 bv = wv[((h*8 + kt)*4 + ct)*64 + l];
      acc[ct] = __builtin_amdgcn_mfma_f32_16x16x32_f16(af.h, bv.h, acc[ct], 0, 0, 0);
    }
  }
  int jb = i0 + g*4;
#pragma unroll
  for (int ct = 0; ct < 4; ++ct) {
    size_t base = ((((size_t)h*128 + (jb>>5))*4 + ct)*64 + ((jb>>3)&3)*16 + r) * 8
                  + (jb & 7);
    union { short4 s; _Float16 hh[4]; } sv;
#pragma unroll
    for (int ri = 0; ri < 4; ++ri) sv.hh[ri] = (_Float16)acc[ct][ri];
    *(short4*)(bfrag + base) = sv.s;
  }
  float a1v[4], a2v[4];
#pragma unroll
  for (int ct = 0; ct < 4; ++ct) {
    a1v[ct] = a[h*128 + ct*16 + r];
    a2v[ct] = a[h*128 + 64 + ct*16 + r];
  }
#pragma unroll
  for (int ri = 0; ri < 4; ++ri) {
    float s1 = acc[0][ri]*a1v[0] + acc[1][ri]*a1v[1]
             + acc[2][ri]*a1v[2] + acc[3][ri]*a1v[3];
    float s2 = acc[0][ri]*a2v[0] + acc[1][ri]*a2v[1]
             + acc[2][ri]*a2v[2] + acc[3][ri]*a2v[3];
#pragma unroll
    for (int off = 1; off < 16; off <<= 1) {
      s1 += __shfl_xor(s1, off);
      s2 += __shfl_xor(s2, off);
    }
    if (r == 0) {
      int row = i0 + g*4 + ri;
      f1[h*4096 + row] = s1;
      Gp[h*4096 + row] = (_Float16)__expf(s2);
      Gn[h*4096 + row] = (_Float16)__expf(ALPHA * s2);
    }
  }
}

#define ATTN_BODY(PF, JT, DOPF) {                                              \
  U4 gp, gn;                                                                   \
  gp.u = Gs0[(JT)*4 + g].u;                                                    \
  gn.u = Gs1[(JT)*4 + g].u;                                                    \
  U4 b0, b1, b2, b3;                                                           \
  b0.u = PF[0]; b1.u = PF[1]; b2.u = PF[2]; b3.u = PF[3];                      \
  _Pragma("unroll")                                                            \
  for (int rg = 0; rg < 4; ++rg) {                                             \
    unsigned wm = Lb[rg*16 + r][JT];                                           \
    U4 av;                                                                     \
    _Pragma("unroll")                                                          \
    for (int p = 0; p < 4; ++p) {                                              \
      unsigned pm = pkmax(pkmul(Epp[rg], gp.w[p]), pkmul(Enn[rg], gn.w[p]));   \
      av.w[p] = pm & MLUT[(wm >> (g8 + 2*p)) & 3u];                            \
    }                                                                          \
    acc[rg][0] = __builtin_amdgcn_mfma_f32_16x16x32_f16(av.h, b0.h, acc[rg][0], 0,0,0); \
    acc[rg][1] = __builtin_amdgcn_mfma_f32_16x16x32_f16(av.h, b1.h, acc[rg][1], 0,0,0); \
    acc[rg][2] = __builtin_amdgcn_mfma_f32_16x16x32_f16(av.h, b2.h, acc[rg][2], 0,0,0); \
    acc[rg][3] = __builtin_amdgcn_mfma_f32_16x16x32_f16(av.h, b3.h, acc[rg][3], 0,0,0); \
    unsigned sden = pkadd(pkadd(av.w[0], av.w[1]), pkadd(av.w[2], av.w[3]));   \
    den[rg] += h2f((unsigned short)(sden & 0xFFFFu))                           \
             + h2f((unsigned short)(sden >> 16));                              \
  }                                                                            \
  if (DOPF) {                                                                  \
    _Pragma("unroll")                                                          \
    for (int c = 0; c < 4; ++c) PF[c] = bfh[((JT) + 2)*256 + c*64];            \
  }                                                                            \
}

#define WRBUF(i) {                                                             \
  _Pragma("unroll")                                                            \
  for (int rg = 0; rg < 4; ++rg)                                               \
    _Pragma("unroll")                                                          \
    for (int ct = 0; ct < 4; ++ct) redp[(i)*1088 + (rg*4+ct)*64 + l] = acc[rg][ct]; \
  f32x4 dv = {den[0], den[1], den[2], den[3]};                                 \
  redp[(i)*1088 + 1024 + l] = dv;                                              \
}
#define ADBUF(i) {                                                             \
  _Pragma("unroll")                                                            \
  for (int rg = 0; rg < 4; ++rg)                                               \
    _Pragma("unroll")                                                          \
    for (int ct = 0; ct < 4; ++ct) acc[rg][ct] += redp[(i)*1088 + (rg*4+ct)*64 + l]; \
  f32x4 dv = redp[(i)*1088 + 1024 + l];                                        \
  den[0] += dv[0]; den[1] += dv[1]; den[2] += dv[2]; den[3] += dv[3];          \
}

// k_attn v7: block=(head, 64 rows) x 256 thr; 4 waves = 4 j-quarters, each
// wave owns all 64 rows (4 rowgroups) -> each B quarter read once per block
// (256 MB L2 traffic). ~140 regs, launch_bounds(256,3) -> 3 waves/SIMD.
__global__ __launch_bounds__(256, 3) void k_attn(
    const float* __restrict__ f1, const unsigned int* __restrict__ adjbits,
    const _Float16* __restrict__ Gp, const _Float16* __restrict__ Gn,
    const _Float16* __restrict__ bfrag, float* __restrict__ out) {
  __shared__ __align__(16) char smem[49408];
  __shared__ unsigned MLUT[4];
  unsigned (*Lb)[129] = (unsigned(*)[129])smem;    // 33024 B adjacency bits
  U4* Gs0 = (U4*)(smem + 33024);                   // 8 KB exp(f2)
  U4* Gs1 = (U4*)(smem + 41216);                   // 8 KB exp(a*f2)
  f32x4* redp = (f32x4*)smem;                      // overlay after main loop
  int b = blockIdx.x;
  int h = b & 7, rs = b >> 3;                      // head <-> XCD L2 locality
  int i0 = rs * 64;
  int t = threadIdx.x, jq = t >> 6, l = t & 63;
  int r = l & 15, g = l >> 4, g8 = g * 8;
  if (t < 4) MLUT[t] = ((t & 1) ? 0xFFFFu : 0u) | ((t & 2) ? 0xFFFF0000u : 0u);
  // B prefetch issued before staging (latency hidden under LDS fills)
  const uint4* bfh = (const uint4*)bfrag + (size_t)h * 32768 + l;
  int jt0 = jq * 32;
  uint4 pA[4], pB[4];
#pragma unroll
  for (int c = 0; c < 4; ++c) pA[c] = bfh[jt0 * 256 + c*64];
#pragma unroll
  for (int c = 0; c < 4; ++c) pB[c] = bfh[(jt0 + 1) * 256 + c*64];
  for (int q = t; q < 8192; q += 256)
    Lb[q >> 7][q & 127] = adjbits[(size_t)(i0 + (q >> 7)) * 128 + (q & 127)];
  {
    const uint4* gp4 = (const uint4*)(Gp + (size_t)h * 4096);
    const uint4* gn4 = (const uint4*)(Gn + (size_t)h * 4096);
    for (int q = t; q < 512; q += 256) {           // FULL 512-entry stage (bugfix)
      Gs0[q].u = gp4[q];
      Gs1[q].u = gn4[q];
    }
  }
  unsigned Epp[4], Enn[4];
#pragma unroll
  for (int rg = 0; rg < 4; ++rg) {
    float f1r = f1[h * N_NODES + i0 + rg*16 + r];
    unsigned short ep = f2h_bits(__expf(f1r));
    unsigned short en = f2h_bits(__expf(ALPHA * f1r));
    Epp[rg] = ep | ((unsigned)ep << 16);
    Enn[rg] = en | ((unsigned)en << 16);
  }
  __syncthreads();
  f32x4 z = {0.f,0.f,0.f,0.f};
  f32x4 acc[4][4] = {{z,z,z,z},{z,z,z,z},{z,z,z,z},{z,z,z,z}};
  float den[4] = {0.f, 0.f, 0.f, 0.f};
  for (int q2 = 0; q2 < 16; ++q2) {
    ATTN_BODY(pA, jt0 + q2*2,     (q2 < 15));
    ATTN_BODY(pB, jt0 + q2*2 + 1, (q2 < 15));
  }
  __syncthreads();                                 // Lb/Gs dead; redp overlays
  // cross-jq tree: jq1->buf0, jq3->buf1; jq0/jq2 add; jq2->buf0; jq0 adds
  if (jq == 1) WRBUF(0);
  if (jq == 3) WRBUF(1);
  __syncthreads();
  if (jq == 0) ADBUF(0);
  if (jq == 2) ADBUF(1);
  __syncthreads();
  if (jq == 2) WRBUF(0);
  __syncthreads();
  if (jq == 0) {
    ADBUF(0);
#pragma unroll
    for (int rg = 0; rg < 4; ++rg) {
      den[rg] += __shfl_xor(den[rg], 16);
      den[rg] += __shfl_xor(den[rg], 32);          // all lanes: den of row rg*16+(l&15)
    }
#pragma unroll
    for (int rg = 0; rg < 4; ++rg)
#pragma unroll
      for (int ri = 0; ri < 4; ++ri) {
        float dr = __shfl(den[rg], g*4 + ri);      // lane g*4+ri holds that row
        float sc = 0.125f / dr;
        float* op = out + (size_t)(i0 + rg*16 + g*4 + ri) * 64;
        atomicAdd(op + r,      acc[rg][0][ri] * sc);
        atomicAdd(op + 16 + r, acc[rg][1][ri] * sc);
        atomicAdd(op + 32 + r, acc[rg][2][ri] * sc);
        atomicAdd(op + 48 + r, acc[rg][3][ri] * sc);
      }
  }
}

extern "C" void kernel_launch(void* const* d_in, const int* in_sizes, int n_in,
                              void* d_out, int out_size, void* d_ws, size_t ws_size,
                              hipStream_t stream) {
  const float* X = (const float*)d_in[0];
  const int* adj = (const int*)d_in[1];
  const float* W = (const float*)d_in[2];
  const float* a = (const float*)d_in[3];
  float* out = (float*)d_out;
  char* ws = (char*)d_ws;

  _Float16* wfrag = (_Float16*)(ws + WFRAG_OFF);
  _Float16* bfrag = (_Float16*)(ws + BFRAG_OFF);
  float* f1 = (float*)(ws + F1_OFF);
  _Float16* Gp = (_Float16*)(ws + GP_OFF);
  _Float16* Gn = (_Float16*)(ws + GN_OFF);
  unsigned long long* bits64 = (unsigned long long*)(ws + ADJ_OFF);
  const unsigned int* bits32 = (const unsigned int*)(ws + ADJ_OFF);

  k_pre<<<dim3(16), dim3(256), 0, stream>>>(W, wfrag, out);
  k_main<<<dim3(2560), dim3(256), 0, stream>>>(X, adj, wfrag, a, bits64, bfrag,
                                               f1, Gp, Gn);
  k_attn<<<dim3(512), dim3(256), 0, stream>>>(f1, bits32, Gp, Gn, bfrag, out);
}

// Round 11
// 71.925 us; speedup vs baseline: 1.8877x; 1.0385x over previous
//
#include <hip/hip_runtime.h>
#include <hip/hip_bf16.h>

#define N_NODES 4096
#define IN_F 256
#define OUT_F 64
#define HEADS 8
#define ALPHA 0.2f

typedef _Float16 f16x8 __attribute__((ext_vector_type(8)));
typedef float f32x4 __attribute__((ext_vector_type(4)));
union U4 { uint4 u; f16x8 h; unsigned w[4]; };

// ---- workspace layout (bytes) ----
#define WFRAG_OFF 0                                 // 256 KB f16 W B-frags
#define BFRAG_OFF (WFRAG_OFF + 8*8*4*64*8*2)        // 4 MB  f16 H B-frags
#define F1_OFF    (BFRAG_OFF + 8*128*4*64*8*2)      // 128 KB f32 f1
#define GP_OFF    (F1_OFF + 8*4096*4)               // 64 KB f16 exp(f2)
#define GN_OFF    (GP_OFF + 8*4096*2)               // 64 KB f16 exp(a*f2)
#define ADJ_OFF   (GN_OFF + 8*4096*2)               // 2 MB adjacency bitmask

static __device__ __forceinline__ unsigned pkmul(unsigned a, unsigned b) {
  unsigned r; asm("v_pk_mul_f16 %0, %1, %2" : "=v"(r) : "v"(a), "v"(b)); return r;
}
static __device__ __forceinline__ unsigned pkmax(unsigned a, unsigned b) {
  unsigned r; asm("v_pk_max_f16 %0, %1, %2" : "=v"(r) : "v"(a), "v"(b)); return r;
}
static __device__ __forceinline__ unsigned short f2h_bits(float f) {
  return __builtin_bit_cast(unsigned short, (_Float16)f);
}

// k_pre: [0,8) W -> B-frag layout; [8,16) zero out
__global__ __launch_bounds__(256) void k_pre(const float* __restrict__ W,
                                             _Float16* __restrict__ wfrag,
                                             float* __restrict__ out) {
  int b = blockIdx.x, t = threadIdx.x;
  if (b < 8) {
    int h = b;
    for (int pos = t; pos < 2048; pos += 256) {
      int kt = pos >> 8, ct = (pos >> 6) & 3, l = pos & 63;
      int lr = l & 15, lg = l >> 4;
#pragma unroll
      for (int e = 0; e < 8; ++e)
        wfrag[(size_t)(((h*8 + kt)*4 + ct)*64 + l) * 8 + e]
          = (_Float16)W[(size_t)(h*256 + kt*32 + lg*8 + e) * 64 + ct*16 + lr];
    }
  } else {
    float4* oz = ((float4*)out) + (size_t)(b - 8) * 8192;
    float4 zz = make_float4(0.f, 0.f, 0.f, 0.f);
    for (int q = t; q < 8192; q += 256) oz[q] = zz;
  }
}

// k_main: [0,512) H=X@W (f16 MFMA, no LDS) + f1/Gp/Gn epilogue;
//         [512,2560) adj->bitmask, unroll x4, nontemporal loads
__global__ __launch_bounds__(256) void k_main(
    const float* __restrict__ X, const int* __restrict__ adj,
    const _Float16* __restrict__ wfrag, const float* __restrict__ a,
    unsigned long long* __restrict__ bits, _Float16* __restrict__ bfrag,
    float* __restrict__ f1, _Float16* __restrict__ Gp, _Float16* __restrict__ Gn) {
  int b = blockIdx.x, t = threadIdx.x;
  if (b >= 512) {
    int b2 = b - 512;
    int lane = t & 63;
    int waveid = b2 * 4 + (t >> 6);
#pragma unroll
    for (int it2 = 0; it2 < 8; ++it2) {
      int w0 = waveid + (it2*4 + 0) * 8192;
      int w1 = waveid + (it2*4 + 1) * 8192;
      int w2 = waveid + (it2*4 + 2) * 8192;
      int w3 = waveid + (it2*4 + 3) * 8192;
      int v0 = __builtin_nontemporal_load(adj + (size_t)w0 * 64 + lane);
      int v1 = __builtin_nontemporal_load(adj + (size_t)w1 * 64 + lane);
      int v2 = __builtin_nontemporal_load(adj + (size_t)w2 * 64 + lane);
      int v3 = __builtin_nontemporal_load(adj + (size_t)w3 * 64 + lane);
      unsigned long long m0 = __ballot(v0 != 0);
      unsigned long long m1 = __ballot(v1 != 0);
      unsigned long long m2 = __ballot(v2 != 0);
      unsigned long long m3 = __ballot(v3 != 0);
      if (lane == 0) { bits[w0] = m0; bits[w1] = m1; bits[w2] = m2; bits[w3] = m3; }
    }
    return;
  }
  int h = b & 7, rb = b >> 3;
  int w = t >> 6, l = t & 63;
  int i0 = rb * 64 + w * 16;                       // 16 rows per wave
  int r = l & 15, g = l >> 4;
  const U4* wv = (const U4*)wfrag;
  f32x4 z = {0.f, 0.f, 0.f, 0.f};
  f32x4 acc[4] = {z, z, z, z};
#pragma unroll
  for (int kt = 0; kt < 8; ++kt) {
    const float4* xr = (const float4*)(X + (size_t)(i0 + r) * 256 + (kt*4 + g) * 8);
    float4 x0 = xr[0], x1 = xr[1];
    U4 af;
    af.h[0] = (_Float16)x0.x; af.h[1] = (_Float16)x0.y;
    af.h[2] = (_Float16)x0.z; af.h[3] = (_Float16)x0.w;
    af.h[4] = (_Float16)x1.x; af.h[5] = (_Float16)x1.y;
    af.h[6] = (_Float16)x1.z; af.h[7] = (_Float16)x1.w;
#pragma unroll
    for (int ct = 0; ct < 4; ++ct) {
      U4 bv = wv[((h*8 + kt)*4 + ct)*64 + l];
      acc[ct] = __builtin_amdgcn_mfma_f32_16x16x32_f16(af.h, bv.h, acc[ct], 0, 0, 0);
    }
  }
  int jb = i0 + g*4;
#pragma unroll
  for (int ct = 0; ct < 4; ++ct) {
    size_t base = ((((size_t)h*128 + (jb>>5))*4 + ct)*64 + ((jb>>3)&3)*16 + r) * 8
                  + (jb & 7);
    union { short4 s; _Float16 hh[4]; } sv;
#pragma unroll
    for (int ri = 0; ri < 4; ++ri) sv.hh[ri] = (_Float16)acc[ct][ri];
    *(short4*)(bfrag + base) = sv.s;
  }
  float a1v[4], a2v[4];
#pragma unroll
  for (int ct = 0; ct < 4; ++ct) {
    a1v[ct] = a[h*128 + ct*16 + r];
    a2v[ct] = a[h*128 + 64 + ct*16 + r];
  }
#pragma unroll
  for (int ri = 0; ri < 4; ++ri) {
    float s1 = acc[0][ri]*a1v[0] + acc[1][ri]*a1v[1]
             + acc[2][ri]*a1v[2] + acc[3][ri]*a1v[3];
    float s2 = acc[0][ri]*a2v[0] + acc[1][ri]*a2v[1]
             + acc[2][ri]*a2v[2] + acc[3][ri]*a2v[3];
#pragma unroll
    for (int off = 1; off < 16; off <<= 1) {
      s1 += __shfl_xor(s1, off);
      s2 += __shfl_xor(s2, off);
    }
    if (r == 0) {
      int row = i0 + g*4 + ri;
      f1[h*4096 + row] = s1;
      Gp[h*4096 + row] = (_Float16)__expf(s2);
      Gn[h*4096 + row] = (_Float16)__expf(ALPHA * s2);
    }
  }
}

#define ATTN_BODY(PF, JT, DOPF) {                                              \
  U4 gp, gn;                                                                   \
  gp.u = Gs0[(JT)*4 + g].u;                                                    \
  gn.u = Gs1[(JT)*4 + g].u;                                                    \
  U4 b0, b1, b2, b3;                                                           \
  b0.u = PF[0]; b1.u = PF[1]; b2.u = PF[2]; b3.u = PF[3];                      \
  _Pragma("unroll")                                                            \
  for (int rg = 0; rg < 2; ++rg) {                                             \
    unsigned wm = Lb[rh32 + rg*16 + r][JT];                                    \
    U4 av;                                                                     \
    _Pragma("unroll")                                                          \
    for (int p = 0; p < 4; ++p) {                                              \
      unsigned pm = pkmax(pkmul(Epp[rg], gp.w[p]), pkmul(Enn[rg], gn.w[p]));   \
      av.w[p] = pm & MLUT[(wm >> (g8 + 2*p)) & 3u];                            \
    }                                                                          \
    acc[rg][0] = __builtin_amdgcn_mfma_f32_16x16x32_f16(av.h, b0.h, acc[rg][0], 0,0,0); \
    acc[rg][1] = __builtin_amdgcn_mfma_f32_16x16x32_f16(av.h, b1.h, acc[rg][1], 0,0,0); \
    acc[rg][2] = __builtin_amdgcn_mfma_f32_16x16x32_f16(av.h, b2.h, acc[rg][2], 0,0,0); \
    acc[rg][3] = __builtin_amdgcn_mfma_f32_16x16x32_f16(av.h, b3.h, acc[rg][3], 0,0,0); \
    dn[rg]     = __builtin_amdgcn_mfma_f32_16x16x32_f16(av.h, bones.h, dn[rg], 0,0,0);  \
  }                                                                            \
  if (DOPF) {                                                                  \
    _Pragma("unroll")                                                          \
    for (int c = 0; c < 4; ++c) PF[c] = bfh[((JT) + 2)*256 + c*64];            \
  }                                                                            \
}

#define WRBUF(i) {                                                             \
  _Pragma("unroll")                                                            \
  for (int rg = 0; rg < 2; ++rg) {                                             \
    _Pragma("unroll")                                                          \
    for (int ct = 0; ct < 4; ++ct) redp[(i)*640 + (rg*4+ct)*64 + l] = acc[rg][ct]; \
    redp[(i)*640 + 512 + rg*64 + l] = dn[rg];                                  \
  } }
#define ADBUF(i) {                                                             \
  _Pragma("unroll")                                                            \
  for (int rg = 0; rg < 2; ++rg) {                                             \
    _Pragma("unroll")                                                          \
    for (int ct = 0; ct < 4; ++ct) acc[rg][ct] += redp[(i)*640 + (rg*4+ct)*64 + l]; \
    dn[rg] += redp[(i)*640 + 512 + rg*64 + l];                                 \
  } }

// k_attn v8 (= r8 v6 + den-MFMA): block=(head, 64 rows) x 512 thr;
// 8 waves = 2 row-halves x 4 jq; 32 rows/wave -> acc 32 + dn 8 AGPR,
// ~115 regs -> 4 waves/SIMD; 16 waves/CU. 2-deep private B prefetch.
__global__ __launch_bounds__(512, 4) void k_attn(
    const float* __restrict__ f1, const unsigned int* __restrict__ adjbits,
    const _Float16* __restrict__ Gp, const _Float16* __restrict__ Gn,
    const _Float16* __restrict__ bfrag, float* __restrict__ out) {
  __shared__ __align__(16) char smem[49408];
  __shared__ unsigned MLUT[4];
  unsigned (*Lb)[129] = (unsigned(*)[129])smem;    // 33024 B adjacency bits
  U4* Gs0 = (U4*)(smem + 33024);                   // 8 KB exp(f2)
  U4* Gs1 = (U4*)(smem + 41216);                   // 8 KB exp(a*f2)
  f32x4* redp = (f32x4*)smem;                      // overlay after main loop
  int b = blockIdx.x;
  int h = b & 7, rs = b >> 3;                      // head <-> XCD L2 locality
  int i0 = rs * 64;
  int t = threadIdx.x, wid = t >> 6, l = t & 63;
  int rh = wid >> 2, jq = wid & 3;
  int rh32 = rh * 32;
  int r = l & 15, g = l >> 4, g8 = g * 8;
  if (t < 4) MLUT[t] = ((t & 1) ? 0xFFFFu : 0u) | ((t & 2) ? 0xFFFF0000u : 0u);
  // B prefetch issued before staging (latency hidden under LDS fills)
  const uint4* bfh = (const uint4*)bfrag + (size_t)h * 32768 + l;
  int jt0 = jq * 32;
  uint4 pA[4], pB[4];
#pragma unroll
  for (int c = 0; c < 4; ++c) pA[c] = bfh[jt0 * 256 + c*64];
#pragma unroll
  for (int c = 0; c < 4; ++c) pB[c] = bfh[(jt0 + 1) * 256 + c*64];
  for (int q = t; q < 8192; q += 512)
    Lb[q >> 7][q & 127] = adjbits[(size_t)(i0 + (q >> 7)) * 128 + (q & 127)];
  Gs0[t].u = ((const uint4*)(Gp + (size_t)h * 4096))[t];
  Gs1[t].u = ((const uint4*)(Gn + (size_t)h * 4096))[t];
  unsigned Epp[2], Enn[2];
#pragma unroll
  for (int rg = 0; rg < 2; ++rg) {
    float f1r = f1[h * N_NODES + i0 + rh32 + rg*16 + r];
    unsigned short ep = f2h_bits(__expf(f1r));
    unsigned short en = f2h_bits(__expf(ALPHA * f1r));
    Epp[rg] = ep | ((unsigned)ep << 16);
    Enn[rg] = en | ((unsigned)en << 16);
  }
  unsigned ov = (r == 0) ? 0x3C003C00u : 0u;       // ones col-0 B-frag (f16 1.0)
  U4 bones; bones.u = make_uint4(ov, ov, ov, ov);
  __syncthreads();
  f32x4 z = {0.f,0.f,0.f,0.f};
  f32x4 acc[2][4] = {{z,z,z,z},{z,z,z,z}};
  f32x4 dn[2] = {z, z};
  for (int q2 = 0; q2 < 16; ++q2) {
    ATTN_BODY(pA, jt0 + q2*2,     (q2 < 15));
    ATTN_BODY(pB, jt0 + q2*2 + 1, (q2 < 15));
  }
  __syncthreads();                                 // Lb/Gs dead; redp overlays
  // cross-jq tree per rh: (jq1,jq3)->bufs, (jq0,jq2) add; jq2->buf, jq0 adds
  if (jq == 1 || jq == 3) WRBUF(rh*2 + (jq >> 1));
  __syncthreads();
  if (jq == 0) ADBUF(rh*2);
  if (jq == 2) ADBUF(rh*2 + 1);
  __syncthreads();
  if (jq == 2) WRBUF(rh);
  __syncthreads();
  if (jq == 0) {
    ADBUF(rh);
#pragma unroll
    for (int rg = 0; rg < 2; ++rg)
#pragma unroll
      for (int ri = 0; ri < 4; ++ri) {
        float dr = __shfl(dn[rg][ri], l & 48);     // col-0 lane of this g-group
        float sc = 0.125f / dr;
        float* op = out + (size_t)(i0 + rh32 + rg*16 + g*4 + ri) * 64;
        atomicAdd(op + r,      acc[rg][0][ri] * sc);
        atomicAdd(op + 16 + r, acc[rg][1][ri] * sc);
        atomicAdd(op + 32 + r, acc[rg][2][ri] * sc);
        atomicAdd(op + 48 + r, acc[rg][3][ri] * sc);
      }
  }
}

extern "C" void kernel_launch(void* const* d_in, const int* in_sizes, int n_in,
                              void* d_out, int out_size, void* d_ws, size_t ws_size,
                              hipStream_t stream) {
  const float* X = (const float*)d_in[0];
  const int* adj = (const int*)d_in[1];
  const float* W = (const float*)d_in[2];
  const float* a = (const float*)d_in[3];
  float* out = (float*)d_out;
  char* ws = (char*)d_ws;

  _Float16* wfrag = (_Float16*)(ws + WFRAG_OFF);
  _Float16* bfrag = (_Float16*)(ws + BFRAG_OFF);
  float* f1 = (float*)(ws + F1_OFF);
  _Float16* Gp = (_Float16*)(ws + GP_OFF);
  _Float16* Gn = (_Float16*)(ws + GN_OFF);
  unsigned long long* bits64 = (unsigned long long*)(ws + ADJ_OFF);
  const unsigned int* bits32 = (const unsigned int*)(ws + ADJ_OFF);

  k_pre<<<dim3(16), dim3(256), 0, stream>>>(W, wfrag, out);
  k_main<<<dim3(2560), dim3(256), 0, stream>>>(X, adj, wfrag, a, bits64, bfrag,
                                               f1, Gp, Gn);
  k_attn<<<dim3(512), dim3(512), 0, stream>>>(f1, bits32, Gp, Gn, bfrag, out);
}